// Round 6
// baseline (207.532 us; speedup 1.0000x reference)
//
#include <hip/hip_runtime.h>
#include <hip/hip_bf16.h>

#define HH 8
#define DKK 32
#define DM 256
#define NN 512
#define DE 40
#define DHID 32

__device__ __forceinline__ unsigned short f2bf(float x) {
    union { __hip_bfloat16 h; unsigned short u; } c;
    c.h = __float2bfloat16(x);
    return c.u;
}
__device__ __forceinline__ float bf2f(unsigned short u) {
    return __uint_as_float(((unsigned int)u) << 16);
}
__device__ __forceinline__ float bf_lo(unsigned int u) {
    return __uint_as_float(u << 16);
}
__device__ __forceinline__ float bf_hi(unsigned int u) {
    return __uint_as_float(u & 0xffff0000u);
}

// ---------------- Q/K/V projection: 4 rows per block (row-major) ----------------
__global__ __launch_bounds__(256) void proj_kernel(
    const float* __restrict__ query, const float* __restrict__ key_,
    const float* __restrict__ value,
    const float* __restrict__ Wq, const float* __restrict__ bq,
    const float* __restrict__ Wk, const float* __restrict__ bk,
    const float* __restrict__ Wv, const float* __restrict__ bv,
    float* __restrict__ Q, float* __restrict__ K, float* __restrict__ V)
{
    const int r0 = blockIdx.x * 4;
    const int c = threadIdx.x;
    float aq[4], ak[4], av[4];
    const float bqc = bq[c], bkc = bk[c], bvc = bv[c];
#pragma unroll
    for (int r = 0; r < 4; ++r) { aq[r] = bqc; ak[r] = bkc; av[r] = bvc; }
    for (int k = 0; k < DM; ++k) {
        const float wq = Wq[k*DM + c];
        const float wk = Wk[k*DM + c];
        const float wv = Wv[k*DM + c];
#pragma unroll
        for (int r = 0; r < 4; ++r) {
            aq[r] = fmaf(query[(size_t)(r0+r)*DM + k], wq, aq[r]);   // uniform x
            ak[r] = fmaf(key_ [(size_t)(r0+r)*DM + k], wk, ak[r]);
            av[r] = fmaf(value[(size_t)(r0+r)*DM + k], wv, av[r]);
        }
    }
#pragma unroll
    for (int r = 0; r < 4; ++r) {
        Q[(size_t)(r0+r)*DM + c] = aq[r];
        K[(size_t)(r0+r)*DM + c] = ak[r];
        V[(size_t)(r0+r)*DM + c] = av[r];
    }
}

// ---------------- s1[b,h,i,j] = inv * q_h(i).k_h(j), bf16 out ----------------
__global__ __launch_bounds__(256) void s1_kernel(
    const float* __restrict__ Q, const float* __restrict__ K,
    unsigned short* __restrict__ s1)
{
    const int tid = threadIdx.x;
    const int bh = blockIdx.y, b = bh >> 3, hh = bh & 7;
    const int ti = (blockIdx.x >> 3) * 64, tj = (blockIdx.x & 7) * 64;
    __shared__ float Qt[64][33];
    __shared__ float Kt[64][33];
    const int c = tid & 31, r0 = tid >> 5;
#pragma unroll
    for (int s = 0; s < 8; ++s) {
        Qt[r0 + 8*s][c] = Q[(size_t)(b*NN + ti + r0 + 8*s)*DM + hh*DKK + c];
        Kt[r0 + 8*s][c] = K[(size_t)(b*NN + tj + r0 + 8*s)*DM + hh*DKK + c];
    }
    __syncthreads();
    const int tx = tid & 15, ty = tid >> 4;
    float acc[4][4] = {};
#pragma unroll
    for (int k = 0; k < DKK; ++k) {
        float qv[4], kv[4];
#pragma unroll
        for (int u = 0; u < 4; ++u) { qv[u] = Qt[ty*4+u][k]; kv[u] = Kt[tx*4+u][k]; }
#pragma unroll
        for (int ri = 0; ri < 4; ++ri)
#pragma unroll
            for (int cj = 0; cj < 4; ++cj)
                acc[ri][cj] = fmaf(qv[ri], kv[cj], acc[ri][cj]);
    }
    const float inv = 0.17677669529663687f;
#pragma unroll
    for (int ri = 0; ri < 4; ++ri) {
        ushort4 o;
        o.x = f2bf(acc[ri][0]*inv); o.y = f2bf(acc[ri][1]*inv);
        o.z = f2bf(acc[ri][2]*inv); o.w = f2bf(acc[ri][3]*inv);
        *(ushort4*)(s1 + ((size_t)(b*HH + hh)*NN + ti + ty*4 + ri)*NN + tj + tx*4) = o;
    }
}

// ---------------- chunk kernel: one block per (row i, 256-j chunk) ----------------
__global__ __launch_bounds__(256) void chunk_kernel(
    const float* __restrict__ edges, const int* __restrict__ mask,
    const float* __restrict__ rkW1, const float* __restrict__ rkb1,
    const float* __restrict__ rkW2, const float* __restrict__ rkb2,
    const float* __restrict__ rvW1, const float* __restrict__ rvb1,
    const float* __restrict__ vvec,
    const float* __restrict__ Q, const float* __restrict__ K, const float* __restrict__ V,
    const unsigned short* __restrict__ s1u,
    float* __restrict__ ws_m, float* __restrict__ ws_z,
    float* __restrict__ ws_A, float* __restrict__ ws_O)
{
    const int bid = blockIdx.x;
    const int bi = bid >> 1, cc = bid & 1;
    const int b  = bi >> 9, i = bi & 511;
    const int tid = threadIdx.x;
    const int h = tid >> 5, l = tid & 31;
    const int wid = tid >> 6, lane = tid & 63;
    const int team = tid >> 6, qq = tid & 63, hq = qq >> 3;
    const float inv = 0.17677669529663687f;

    __shared__ __align__(16) unsigned short ch16[32*258];  // h1v^T bf16
    __shared__ __align__(16) unsigned short pb[8*258];     // p bf16 (overlaid wf in prologue)
    __shared__ __align__(16) float gKs[HH*DKK];
    __shared__ float c0Ks[HH];
    __shared__ float redm[32], redz[32];

    float* wf = (float*)pb;   // wf dead before pb is written

    const size_t ebase = (size_t)b*DE*NN*NN + (size_t)i*NN;
    const float* qrow = Q + (size_t)bi*DM;

    // ---- w = inv*(q+k) + v ----
    wf[tid] = inv*(qrow[tid] + K[(size_t)bi*DM + tid]) + vvec[tid];
    __syncthreads();

    // ---- gK[h,t] = rkW2[t, h*32:].w[h,:]; c0K[h] = rkb2[h,:].w[h,:] ----
    {
        float acc = 0.f;
#pragma unroll
        for (int d4 = 0; d4 < DKK/4; ++d4) {
            const float4 w4 = *(const float4*)(rkW2 + (size_t)l*DM + h*DKK + d4*4);
            const float4 f4 = *(const float4*)(&wf[h*DKK + d4*4]);
            acc = fmaf(w4.x, f4.x, acc); acc = fmaf(w4.y, f4.y, acc);
            acc = fmaf(w4.z, f4.z, acc); acc = fmaf(w4.w, f4.w, acc);
        }
        gKs[h*DKK + l] = acc;
        if (tid < HH) {
            float a2 = 0.f;
#pragma unroll
            for (int d = 0; d < DKK; ++d)
                a2 = fmaf(rkb2[tid*DKK + d], wf[tid*DKK + d], a2);
            c0Ks[tid] = a2;
        }
    }
    __syncthreads();   // gKs ready; wf dead from here

    const int j = cc*256 + tid;

    // ---- edge MLP layer-1, both branches (staged loads) ----
    float h1k[DHID], h1v[DHID];
#pragma unroll
    for (int t = 0; t < DHID; ++t) { h1k[t] = rkb1[t]; h1v[t] = rvb1[t]; }
    {
        const float* ep = edges + ebase + j;
#pragma unroll 1
        for (int c0 = 0; c0 < DE; c0 += 10) {
            float ev[10];
#pragma unroll
            for (int u = 0; u < 10; ++u) ev[u] = ep[(size_t)(c0+u)*NN*NN];
#pragma unroll
            for (int u = 0; u < 10; ++u) {
                const float* w1k = rkW1 + (c0+u)*DHID;   // uniform
                const float* w1v = rvW1 + (c0+u)*DHID;
#pragma unroll
                for (int t = 0; t < DHID; ++t) {
                    h1k[t] = fmaf(ev[u], w1k[t], h1k[t]);
                    h1v[t] = fmaf(ev[u], w1v[t], h1v[t]);
                }
            }
        }
    }
#pragma unroll
    for (int t = 0; t < DHID; ++t) {
        h1k[t] = h1k[t] > 0.f ? h1k[t] : 0.1f*h1k[t];
        h1v[t] = h1v[t] > 0.f ? h1v[t] : 0.1f*h1v[t];
    }
#pragma unroll
    for (int t = 0; t < DHID; ++t) ch16[t*258 + tid] = f2bf(h1v[t]);

    // ---- scores in registers: s2 + s1(bf16) + mask ----
    float sreg[HH];
    {
        const int mk = mask[b*NN + j];
        const unsigned short* s1b = s1u + (size_t)b*HH*NN*NN + (size_t)i*NN;
#pragma unroll
        for (int hh = 0; hh < HH; ++hh) {
            float r = c0Ks[hh];
            const float4* g4 = (const float4*)(gKs + hh*DKK);
#pragma unroll
            for (int t4 = 0; t4 < DKK/4; ++t4) {
                const float4 g = g4[t4];
                r = fmaf(g.x, h1k[t4*4+0], r); r = fmaf(g.y, h1k[t4*4+1], r);
                r = fmaf(g.z, h1k[t4*4+2], r); r = fmaf(g.w, h1k[t4*4+3], r);
            }
            r += bf2f(s1b[(size_t)hh*NN*NN + j]);
            sreg[hh] = (mk == 0) ? -1e12f : r;
        }
    }

    // ---- local softmax stats: max (64-lane butterfly + cross-wave) ----
    float m[HH];
#pragma unroll
    for (int hh = 0; hh < HH; ++hh) {
        float v = sreg[hh];
#pragma unroll
        for (int off = 32; off; off >>= 1) v = fmaxf(v, __shfl_xor(v, off));
        m[hh] = v;
    }
    if (lane == 0) {
#pragma unroll
        for (int hh = 0; hh < HH; ++hh) redm[wid*8 + hh] = m[hh];
    }
    __syncthreads();
#pragma unroll
    for (int hh = 0; hh < HH; ++hh)
        m[hh] = fmaxf(fmaxf(redm[hh], redm[8+hh]), fmaxf(redm[16+hh], redm[24+hh]));

    // ---- exp, Z-reduce, publish p (bf16) ----
    float p[HH];
#pragma unroll
    for (int hh = 0; hh < HH; ++hh) p[hh] = __expf(sreg[hh] - m[hh]);
#pragma unroll
    for (int hh = 0; hh < HH; ++hh) {
        float v = p[hh];
#pragma unroll
        for (int off = 32; off; off >>= 1) v += __shfl_xor(v, off);
        if (lane == 0) redz[wid*8 + hh] = v;
    }
#pragma unroll
    for (int hh = 0; hh < HH; ++hh) pb[hh*258 + tid] = f2bf(p[hh]);
    __syncthreads();   // pb, ch16, redz all visible

    if (tid == 0) {
#pragma unroll
        for (int hh = 0; hh < HH; ++hh) {
            ws_m[(size_t)bid*8 + hh] = m[hh];
            ws_z[(size_t)bid*8 + hh] = redz[hh] + redz[8+hh] + redz[16+hh] + redz[24+hh];
        }
    }

    // ---- accA[h,t] = sum_j p[h,j]*h1v[j,t]  (bf16 LDS dwords) ----
    {
        const unsigned int* prow = (const unsigned int*)(pb + h*258);
        const unsigned int* crow = (const unsigned int*)(ch16 + l*258);
        float aA0 = 0.f, aA1 = 0.f;
#pragma unroll 2
        for (int jj = 0; jj < 256; jj += 8) {
            const unsigned int pA = prow[(jj>>1)+0], pB = prow[(jj>>1)+1];
            const unsigned int pC = prow[(jj>>1)+2], pD = prow[(jj>>1)+3];
            const unsigned int cA = crow[(jj>>1)+0], cB = crow[(jj>>1)+1];
            const unsigned int cC = crow[(jj>>1)+2], cD = crow[(jj>>1)+3];
            aA0 = fmaf(bf_lo(pA), bf_lo(cA), aA0); aA0 = fmaf(bf_hi(pA), bf_hi(cA), aA0);
            aA0 = fmaf(bf_lo(pB), bf_lo(cB), aA0); aA0 = fmaf(bf_hi(pB), bf_hi(cB), aA0);
            aA1 = fmaf(bf_lo(pC), bf_lo(cC), aA1); aA1 = fmaf(bf_hi(pC), bf_hi(cC), aA1);
            aA1 = fmaf(bf_lo(pD), bf_lo(cD), aA1); aA1 = fmaf(bf_hi(pD), bf_hi(cD), aA1);
        }
        ws_A[(size_t)bid*256 + tid] = aA0 + aA1;
    }

    // ---- accO team partials: thread owns channels qq*4..+3, j = team (mod 4) ----
    {
        const float* vrow = V + (size_t)b*NN*DM + (size_t)(cc*256 + team)*DM + qq*4;
        const unsigned short* ph = pb + hq*258;
        float aO0 = 0.f, aO1 = 0.f, aO2 = 0.f, aO3 = 0.f;
#pragma unroll 4
        for (int it = 0; it < 64; ++it) {
            const float pp = bf2f(ph[team + 4*it]);
            const float4 v4 = *(const float4*)(vrow + (size_t)it*4*DM);
            aO0 = fmaf(pp, v4.x, aO0); aO1 = fmaf(pp, v4.y, aO1);
            aO2 = fmaf(pp, v4.z, aO2); aO3 = fmaf(pp, v4.w, aO3);
        }
        *(float4*)(ws_O + (size_t)bid*1024 + tid*4) = make_float4(aO0, aO1, aO2, aO3);
    }
}

// ---------------- combine: merge chunks, o2, Wo epilogue. one block per row ----------------
__global__ __launch_bounds__(256) void combine_kernel(
    const float* __restrict__ rvW2, const float* __restrict__ rvb2,
    const float* __restrict__ Wo, const float* __restrict__ bo,
    const float* __restrict__ ws_m, const float* __restrict__ ws_z,
    const float* __restrict__ ws_A, const float* __restrict__ ws_O,
    float* __restrict__ out)
{
    const int bi = blockIdx.x;
    const int tid = threadIdx.x;
    const int h = tid >> 5;
    __shared__ float A_l[DM], o_l[DM];
    __shared__ float w0s[HH], w1s[HH], rzs[HH];

    if (tid < HH) {
        const float m0 = ws_m[(size_t)(bi*2+0)*8 + tid];
        const float m1 = ws_m[(size_t)(bi*2+1)*8 + tid];
        const float z0 = ws_z[(size_t)(bi*2+0)*8 + tid];
        const float z1 = ws_z[(size_t)(bi*2+1)*8 + tid];
        const float mm = fmaxf(m0, m1);
        const float w0 = __expf(m0 - mm), w1 = __expf(m1 - mm);
        w0s[tid] = w0; w1s[tid] = w1;
        rzs[tid] = 1.f / (z0*w0 + z1*w1);
    }
    __syncthreads();

    const float w0 = w0s[h], w1 = w1s[h], rz = rzs[h];
    A_l[tid] = (w0*ws_A[(size_t)(bi*2)*256 + tid] + w1*ws_A[(size_t)(bi*2+1)*256 + tid]) * rz;

    const float* O0 = ws_O + (size_t)(bi*2)*1024;
    float o1 = w0*(O0[tid] + O0[256+tid] + O0[512+tid] + O0[768+tid])
             + w1*(O0[1024+tid] + O0[1280+tid] + O0[1536+tid] + O0[1792+tid]);
    o1 *= rz;
    __syncthreads();

    float o2 = rvb2[tid];
#pragma unroll
    for (int t = 0; t < DHID; ++t)
        o2 = fmaf(A_l[h*DKK + t], rvW2[(size_t)t*DM + tid], o2);
    o_l[tid] = o1 + o2;
    __syncthreads();

    float acc = bo[tid];
#pragma unroll 4
    for (int k = 0; k < DM; ++k)
        acc = fmaf(o_l[k], Wo[(size_t)k*DM + tid], acc);
    out[(size_t)bi*DM + tid] = acc;
}

extern "C" void kernel_launch(void* const* d_in, const int* in_sizes, int n_in,
                              void* d_out, int out_size, void* d_ws, size_t ws_size,
                              hipStream_t stream) {
    const float* query = (const float*)d_in[0];
    const float* key_  = (const float*)d_in[1];
    const float* value = (const float*)d_in[2];
    const float* edges = (const float*)d_in[3];
    const int*   mask  = (const int*)d_in[4];
    const float* Wq = (const float*)d_in[5];
    const float* bq = (const float*)d_in[6];
    const float* Wk = (const float*)d_in[7];
    const float* bk = (const float*)d_in[8];
    const float* Wv = (const float*)d_in[9];
    const float* bv = (const float*)d_in[10];
    const float* Wo = (const float*)d_in[11];
    const float* bo = (const float*)d_in[12];
    const float* rkW1 = (const float*)d_in[13];
    const float* rkb1 = (const float*)d_in[14];
    const float* rkW2 = (const float*)d_in[15];
    const float* rkb2 = (const float*)d_in[16];
    const float* rvW1 = (const float*)d_in[17];
    const float* rvb1 = (const float*)d_in[18];
    const float* rvW2 = (const float*)d_in[19];
    const float* rvb2 = (const float*)d_in[20];
    // d_in[21] (u) is softmax-invariant -> unused
    const float* vvec = (const float*)d_in[22];

    const int rows = in_sizes[0] / DM;       // b*n = 1024
    const int nchunk = rows * 2;             // 2048

    float* Qw  = (float*)d_ws;
    float* Kw  = Qw + (size_t)rows*DM;
    float* Vw  = Kw + (size_t)rows*DM;
    unsigned short* s1u = (unsigned short*)(Vw + (size_t)rows*DM);   // 2*8*512*512 bf16 = 8 MB
    float* ws_m = (float*)(s1u + (size_t)2*HH*NN*NN);
    float* ws_z = ws_m + (size_t)nchunk*8;
    float* ws_A = ws_z + (size_t)nchunk*8;
    float* ws_O = ws_A + (size_t)nchunk*256;

    hipLaunchKernelGGL(proj_kernel, dim3(rows/4), dim3(256), 0, stream,
                       query, key_, value, Wq, bq, Wk, bk, Wv, bv, Qw, Kw, Vw);
    hipLaunchKernelGGL(s1_kernel, dim3(64, 16), dim3(256), 0, stream,
                       Qw, Kw, s1u);
    hipLaunchKernelGGL(chunk_kernel, dim3(nchunk), dim3(256), 0, stream,
                       edges, mask, rkW1, rkb1, rkW2, rkb2, rvW1, rvb1,
                       vvec, Qw, Kw, Vw, s1u, ws_m, ws_z, ws_A, ws_O);
    hipLaunchKernelGGL(combine_kernel, dim3(rows), dim3(256), 0, stream,
                       rvW2, rvb2, Wo, bo, ws_m, ws_z, ws_A, ws_O, (float*)d_out);
}

// Round 7
// 164.759 us; speedup vs baseline: 1.2596x; 1.2596x over previous
//
#include <hip/hip_runtime.h>
#include <hip/hip_bf16.h>

#define HH 8
#define DKK 32
#define DM 256
#define NN 512
#define DE 40
#define DHID 32
#define CH 128
#define NCH 4

typedef __attribute__((ext_vector_type(4))) short short4v;
typedef __attribute__((ext_vector_type(8))) short short8v;
typedef __attribute__((ext_vector_type(4))) float f32x4;

__device__ __forceinline__ unsigned short f2bf(float x) {
    union { __hip_bfloat16 h; unsigned short u; } c;
    c.h = __float2bfloat16(x);
    return c.u;
}
__device__ __forceinline__ float bf2f(unsigned short u) {
    return __uint_as_float(((unsigned int)u) << 16);
}
__device__ __forceinline__ float bf_lo(unsigned int u){ return __uint_as_float(u << 16); }
__device__ __forceinline__ float bf_hi(unsigned int u){ return __uint_as_float(u & 0xffff0000u); }
__device__ __forceinline__ unsigned int pack2bf(float a, float b) {
    return (unsigned int)f2bf(a) | ((unsigned int)f2bf(b) << 16);
}
__device__ __forceinline__ short8v ld8(const unsigned short* p) {
    short4v lo = *(const short4v*)p;
    short4v hi = *(const short4v*)(p + 4);
    short8v r;
    r[0]=lo[0]; r[1]=lo[1]; r[2]=lo[2]; r[3]=lo[3];
    r[4]=hi[0]; r[5]=hi[1]; r[6]=hi[2]; r[7]=hi[3];
    return r;
}

// ---------------- Q/K/V projection: 4 rows per block (row-major) ----------------
__global__ __launch_bounds__(256) void proj_kernel(
    const float* __restrict__ query, const float* __restrict__ key_,
    const float* __restrict__ value,
    const float* __restrict__ Wq, const float* __restrict__ bq,
    const float* __restrict__ Wk, const float* __restrict__ bk,
    const float* __restrict__ Wv, const float* __restrict__ bv,
    float* __restrict__ Q, float* __restrict__ K, float* __restrict__ V)
{
    const int r0 = blockIdx.x * 4;
    const int c = threadIdx.x;
    float aq[4], ak[4], av[4];
    const float bqc = bq[c], bkc = bk[c], bvc = bv[c];
#pragma unroll
    for (int r = 0; r < 4; ++r) { aq[r] = bqc; ak[r] = bkc; av[r] = bvc; }
    for (int k = 0; k < DM; ++k) {
        const float wq = Wq[k*DM + c];
        const float wk = Wk[k*DM + c];
        const float wv = Wv[k*DM + c];
#pragma unroll
        for (int r = 0; r < 4; ++r) {
            aq[r] = fmaf(query[(size_t)(r0+r)*DM + k], wq, aq[r]);   // uniform x
            ak[r] = fmaf(key_ [(size_t)(r0+r)*DM + k], wk, ak[r]);
            av[r] = fmaf(value[(size_t)(r0+r)*DM + k], wv, av[r]);
        }
    }
#pragma unroll
    for (int r = 0; r < 4; ++r) {
        Q[(size_t)(r0+r)*DM + c] = aq[r];
        K[(size_t)(r0+r)*DM + c] = ak[r];
        V[(size_t)(r0+r)*DM + c] = av[r];
    }
}

// ---------------- s1[b,h,i,j] = inv * q_h(i).k_h(j), bf16 out ----------------
__global__ __launch_bounds__(256) void s1_kernel(
    const float* __restrict__ Q, const float* __restrict__ K,
    unsigned short* __restrict__ s1)
{
    const int tid = threadIdx.x;
    const int bh = blockIdx.y, b = bh >> 3, hh = bh & 7;
    const int ti = (blockIdx.x >> 3) * 64, tj = (blockIdx.x & 7) * 64;
    __shared__ float Qt[64][33];
    __shared__ float Kt[64][33];
    const int c = tid & 31, r0 = tid >> 5;
#pragma unroll
    for (int s = 0; s < 8; ++s) {
        Qt[r0 + 8*s][c] = Q[(size_t)(b*NN + ti + r0 + 8*s)*DM + hh*DKK + c];
        Kt[r0 + 8*s][c] = K[(size_t)(b*NN + tj + r0 + 8*s)*DM + hh*DKK + c];
    }
    __syncthreads();
    const int tx = tid & 15, ty = tid >> 4;
    float acc[4][4] = {};
#pragma unroll
    for (int k = 0; k < DKK; ++k) {
        float qv[4], kv[4];
#pragma unroll
        for (int u = 0; u < 4; ++u) { qv[u] = Qt[ty*4+u][k]; kv[u] = Kt[tx*4+u][k]; }
#pragma unroll
        for (int ri = 0; ri < 4; ++ri)
#pragma unroll
            for (int cj = 0; cj < 4; ++cj)
                acc[ri][cj] = fmaf(qv[ri], kv[cj], acc[ri][cj]);
    }
    const float inv = 0.17677669529663687f;
#pragma unroll
    for (int ri = 0; ri < 4; ++ri) {
        ushort4 o;
        o.x = f2bf(acc[ri][0]*inv); o.y = f2bf(acc[ri][1]*inv);
        o.z = f2bf(acc[ri][2]*inv); o.w = f2bf(acc[ri][3]*inv);
        *(ushort4*)(s1 + ((size_t)(b*HH + hh)*NN + ti + ty*4 + ri)*NN + tj + tx*4) = o;
    }
}

// ---------------- fused relative attention: one block per (b,i) row ----------------
// 4 chunks of 128 j, online softmax; edge-MLP layer-1 and accA via MFMA.
__global__ __launch_bounds__(256) void attn_kernel(
    const float* __restrict__ edges, const int* __restrict__ mask,
    const float* __restrict__ rkW1, const float* __restrict__ rkb1,
    const float* __restrict__ rkW2, const float* __restrict__ rkb2,
    const float* __restrict__ rvW1, const float* __restrict__ rvb1,
    const float* __restrict__ rvW2, const float* __restrict__ rvb2,
    const float* __restrict__ vvec,
    const float* __restrict__ Wo, const float* __restrict__ bo,
    const float* __restrict__ Q, const float* __restrict__ K, const float* __restrict__ V,
    const unsigned short* __restrict__ s1u,
    float* __restrict__ out)
{
    const int bi = blockIdx.x;          // b*512 + i
    const int b  = bi >> 9;
    const int i  = bi & 511;
    const int tid = threadIdx.x;
    const int h = tid >> 5, l32 = tid & 31;          // softmax/A mapping
    const int wid = tid >> 6, lane = tid & 63;       // wave mapping (mfma)
    const int g = lane >> 4, q16 = lane & 15;
    const int team = tid >> 6, qq = tid & 63, hq = qq >> 3;  // accO mapping
    const int jj = tid & 127, half = tid >> 7;       // E-load / scores mapping
    const float inv = 0.17677669529663687f;

    // ---- LDS: unioned region + persistent buffers ----
    __shared__ __align__(16) unsigned char uni[17408];
    __shared__ __align__(16) unsigned short W1bf[64*68];     // [n=64][k=68], k 40..67 zero
    __shared__ __align__(16) float sc[HH*132];
    __shared__ __align__(16) float gKs[HH*DKK];
    __shared__ float c0Ks[HH], scl_s[HH];

    unsigned short* E   = (unsigned short*)uni;              // [128][68] bf16
    unsigned short* hvT = (unsigned short*)uni;              // [32][132] bf16
    unsigned short* hk  = (unsigned short*)(uni + 8448);     // [128][34] bf16
    unsigned short* pb  = (unsigned short*)(uni + 8448);     // [16][132] bf16 (in hk space)
    float* wf    = (float*)uni;                              // prologue only
    float* paccA = (float*)uni;                              // [4][256] epilogue
    float* po    = (float*)(uni + 4096);                     // [4][256] epilogue
    float* A_l   = (float*)(uni + 8192);                     // [256]
    float* o_l   = (float*)(uni + 9216);                     // [256]

    const size_t ebase = (size_t)b*DE*NN*NN + (size_t)i*NN;
    const float* qrow = Q + (size_t)bi*DM;

    // ---- prologue: wf, W1bf (combined W1k|W1v bf16, K-padded), bias regs ----
    wf[tid] = inv*(qrow[tid] + K[(size_t)bi*DM + tid]) + vvec[tid];
    {
        const int n = tid >> 2, qd = tid & 3;
#pragma unroll
        for (int kk = 0; kk < 17; ++kk) {
            const int k = qd*17 + kk;
            float v = 0.f;
            if (k < DE) v = (n < 32) ? rkW1[k*DHID + n] : rvW1[k*DHID + (n-32)];
            W1bf[n*68 + k] = f2bf(v);
        }
    }
    float biasv[4];
#pragma unroll
    for (int nt = 0; nt < 4; ++nt) {
        const int n = nt*16 + q16;
        biasv[nt] = (n < 32) ? rkb1[n] : rvb1[n-32];
    }
    __syncthreads();

    // ---- gK[h,t] = rkW2[t, h*32:].w[h,:]; c0K[h] = rkb2[h,:].w[h,:] ----
    {
        float acc = 0.f;
#pragma unroll
        for (int d4 = 0; d4 < DKK/4; ++d4) {
            const float4 w4 = *(const float4*)(rkW2 + (size_t)l32*DM + h*DKK + d4*4);
            const float4 f4 = *(const float4*)(&wf[h*DKK + d4*4]);
            acc = fmaf(w4.x, f4.x, acc); acc = fmaf(w4.y, f4.y, acc);
            acc = fmaf(w4.z, f4.z, acc); acc = fmaf(w4.w, f4.w, acc);
        }
        gKs[h*DKK + l32] = acc;
        if (tid < HH) {
            float a2 = 0.f;
#pragma unroll
            for (int d = 0; d < DKK; ++d)
                a2 = fmaf(rkb2[tid*DKK + d], wf[tid*DKK + d], a2);
            c0Ks[tid] = a2;
        }
    }
    __syncthreads();   // wf dead; E region free

    float m_run = -3e38f, Zacc = 0.f;
    float aO0 = 0.f, aO1 = 0.f, aO2 = 0.f, aO3 = 0.f;
    f32x4 accAf0 = {0.f,0.f,0.f,0.f}, accAf1 = {0.f,0.f,0.f,0.f};
    const float* vb = V + (size_t)b*NN*DM;
    const unsigned short* s1b = s1u + (size_t)b*HH*NN*NN + (size_t)i*NN;

#pragma unroll 1
    for (int ch = 0; ch < NCH; ++ch) {
        const int j0 = ch*CH;

        // ---- E stage: edges -> bf16 LDS [128][68] (cols 40..63 zero) ----
        {
            const float* ep = edges + ebase + j0 + jj;
            float ev[20];
#pragma unroll
            for (int u = 0; u < 20; ++u) ev[u] = ep[(size_t)(half*20+u)*NN*NN];
            unsigned int* Ed = (unsigned int*)&E[jj*68 + half*20];
#pragma unroll
            for (int u = 0; u < 10; ++u) Ed[u] = pack2bf(ev[2*u], ev[2*u+1]);
            if (half) {
                unsigned int* Ez = (unsigned int*)&E[jj*68 + 40];
#pragma unroll
                for (int z = 0; z < 12; ++z) Ez[z] = 0u;
            }
        }
        __syncthreads();

        // ---- h1 = E @ W1 (+bias) via MFMA: wave owns 32 j rows ----
        f32x4 acc[2][4];
        {
            short8v bk0[4], bk1[4];
#pragma unroll
            for (int nt = 0; nt < 4; ++nt) {
                const unsigned short* wp = &W1bf[(q16 + nt*16)*68 + g*8];
                bk0[nt] = ld8(wp);
                bk1[nt] = ld8(wp + 32);
            }
#pragma unroll
            for (int jt = 0; jt < 2; ++jt) {
                const int jn = wid*32 + jt*16 + q16;
                short8v a0 = ld8(&E[jn*68 + g*8]);
                short8v a1 = ld8(&E[jn*68 + 32 + g*8]);
#pragma unroll
                for (int nt = 0; nt < 4; ++nt) {
                    f32x4 c;
                    c[0] = biasv[nt]; c[1] = biasv[nt]; c[2] = biasv[nt]; c[3] = biasv[nt];
                    c = __builtin_amdgcn_mfma_f32_16x16x32_bf16(a0, bk0[nt], c, 0, 0, 0);
                    c = __builtin_amdgcn_mfma_f32_16x16x32_bf16(a1, bk1[nt], c, 0, 0, 0);
                    acc[jt][nt] = c;
                }
            }
        }
        __syncthreads();   // all E reads done before overwrite

        // ---- leaky + writeback: hk[j][t] and hvT[t][j] ----
#pragma unroll
        for (int jt = 0; jt < 2; ++jt) {
            const int jw = wid*32 + jt*16 + g*4;
#pragma unroll
            for (int nt = 0; nt < 4; ++nt) {
#pragma unroll
                for (int r = 0; r < 4; ++r) {
                    float x = acc[jt][nt][r];
                    x = x > 0.f ? x : 0.1f*x;
                    const unsigned short us = f2bf(x);
                    const int n = nt*16 + q16;
                    if (n < 32) hk[(jw+r)*34 + n] = us;
                    else        hvT[(n-32)*132 + (jw+r)] = us;
                }
            }
        }
        __syncthreads();   // hk/hvT ready

        // ---- scores: s2 (gK . h1k) + s1 + mask ----
        {
            unsigned int hku[16];
#pragma unroll
            for (int d = 0; d < 16; ++d) hku[d] = *(const unsigned int*)&hk[jj*34 + 2*d];
            const int mk = mask[b*NN + j0 + jj];
            float racc[4];
#pragma unroll
            for (int u = 0; u < 4; ++u) racc[u] = c0Ks[half*4 + u];
#pragma unroll
            for (int d = 0; d < 16; ++d) {
                const float lo = bf_lo(hku[d]), hi = bf_hi(hku[d]);
#pragma unroll
                for (int u = 0; u < 4; ++u) {
                    const int hh = half*4 + u;
                    racc[u] = fmaf(gKs[hh*DKK + 2*d],     lo, racc[u]);
                    racc[u] = fmaf(gKs[hh*DKK + 2*d + 1], hi, racc[u]);
                }
            }
#pragma unroll
            for (int u = 0; u < 4; ++u) {
                const int hh = half*4 + u;
                float r = racc[u] + bf2f(s1b[(size_t)hh*NN*NN + j0 + jj]);
                if (mk == 0) r = -1e12f;
                sc[hh*132 + jj] = r;
            }
        }
        __syncthreads();

        // ---- online softmax (head h per 32-lane group), publish p bf16 + scl ----
        {
            float sv[4];
            float mc = -3e38f;
#pragma unroll
            for (int k = 0; k < 4; ++k) { sv[k] = sc[h*132 + l32 + 32*k]; mc = fmaxf(mc, sv[k]); }
#pragma unroll
            for (int off = 16; off; off >>= 1) mc = fmaxf(mc, __shfl_xor(mc, off, 32));
            const float mnew = fmaxf(m_run, mc);
            const float scl = __expf(m_run - mnew);
            m_run = mnew;
            Zacc *= scl;
            float zc = 0.f;
#pragma unroll
            for (int k = 0; k < 4; ++k) {
                const float e = __expf(sv[k] - m_run);
                pb[h*132 + l32 + 32*k] = f2bf(e);
                zc += e;
            }
#pragma unroll
            for (int off = 16; off; off >>= 1) zc += __shfl_xor(zc, off, 32);
            Zacc += zc;
            if (l32 == 0) scl_s[h] = scl;
        }
        __syncthreads();   // pb + scl_s visible

        // ---- rescale + accA via MFMA (p[16x128] @ h1v[128x32], wave = K-quarter) ----
        {
            const float s0 = scl_s[(g*4+0)&7], s1r = scl_s[(g*4+1)&7];
            const float s2r = scl_s[(g*4+2)&7], s3r = scl_s[(g*4+3)&7];
            accAf0[0]*=s0; accAf0[1]*=s1r; accAf0[2]*=s2r; accAf0[3]*=s3r;
            accAf1[0]*=s0; accAf1[1]*=s1r; accAf1[2]*=s2r; accAf1[3]*=s3r;
            short8v pA = ld8(&pb[q16*132 + wid*32 + g*8]);
            short8v b0 = ld8(&hvT[q16*132 + wid*32 + g*8]);
            short8v b1 = ld8(&hvT[(16+q16)*132 + wid*32 + g*8]);
            accAf0 = __builtin_amdgcn_mfma_f32_16x16x32_bf16(pA, b0, accAf0, 0, 0, 0);
            accAf1 = __builtin_amdgcn_mfma_f32_16x16x32_bf16(pA, b1, accAf1, 0, 0, 0);

            // ---- accO: channels qq*4..+3, j = j0 + team + 4*it ----
            const float sO = scl_s[hq];
            aO0 *= sO; aO1 *= sO; aO2 *= sO; aO3 *= sO;
            const float* vrow = vb + (size_t)(j0 + team)*DM + qq*4;
            const unsigned short* ph = pb + hq*132 + team;
#pragma unroll 4
            for (int it = 0; it < 32; ++it) {
                const float p = bf2f(ph[4*it]);
                const float4 v4 = *(const float4*)(vrow + (size_t)it*4*DM);
                aO0 = fmaf(p, v4.x, aO0); aO1 = fmaf(p, v4.y, aO1);
                aO2 = fmaf(p, v4.z, aO2); aO3 = fmaf(p, v4.w, aO3);
            }
        }
        __syncthreads();   // chunk consumed; next E overwrite safe
    }

    // ---- epilogue ----
    if (g < 2) {
#pragma unroll
        for (int r = 0; r < 4; ++r) {
            paccA[wid*256 + (4*g+r)*32 + q16]      = accAf0[r];
            paccA[wid*256 + (4*g+r)*32 + 16 + q16] = accAf1[r];
        }
    }
    *(float4*)(po + team*256 + qq*4) = make_float4(aO0, aO1, aO2, aO3);
    __syncthreads();

    const float rz = 1.f / Zacc;   // this thread's head = tid>>5 for both A_l and po rows
    A_l[tid] = (paccA[tid] + paccA[256+tid] + paccA[512+tid] + paccA[768+tid]) * rz;
    const float o1 = (po[tid] + po[256+tid] + po[512+tid] + po[768+tid]) * rz;
    __syncthreads();

    float o2 = rvb2[tid];
#pragma unroll
    for (int t = 0; t < DHID; ++t)
        o2 = fmaf(A_l[(tid>>5)*32 + t], rvW2[(size_t)t*DM + tid], o2);
    o_l[tid] = o1 + o2;
    __syncthreads();

    float accw = bo[tid];
#pragma unroll 4
    for (int k = 0; k < DM; ++k)
        accw = fmaf(o_l[k], Wo[(size_t)k*DM + tid], accw);
    out[(size_t)bi*DM + tid] = accw;
}

extern "C" void kernel_launch(void* const* d_in, const int* in_sizes, int n_in,
                              void* d_out, int out_size, void* d_ws, size_t ws_size,
                              hipStream_t stream) {
    const float* query = (const float*)d_in[0];
    const float* key_  = (const float*)d_in[1];
    const float* value = (const float*)d_in[2];
    const float* edges = (const float*)d_in[3];
    const int*   mask  = (const int*)d_in[4];
    const float* Wq = (const float*)d_in[5];
    const float* bq = (const float*)d_in[6];
    const float* Wk = (const float*)d_in[7];
    const float* bk = (const float*)d_in[8];
    const float* Wv = (const float*)d_in[9];
    const float* bv = (const float*)d_in[10];
    const float* Wo = (const float*)d_in[11];
    const float* bo = (const float*)d_in[12];
    const float* rkW1 = (const float*)d_in[13];
    const float* rkb1 = (const float*)d_in[14];
    const float* rkW2 = (const float*)d_in[15];
    const float* rkb2 = (const float*)d_in[16];
    const float* rvW1 = (const float*)d_in[17];
    const float* rvb1 = (const float*)d_in[18];
    const float* rvW2 = (const float*)d_in[19];
    const float* rvb2 = (const float*)d_in[20];
    // d_in[21] (u) is softmax-invariant -> unused
    const float* vvec = (const float*)d_in[22];

    const int rows = in_sizes[0] / DM;   // b*n = 1024

    float* Qw = (float*)d_ws;
    float* Kw = Qw + (size_t)rows*DM;
    float* Vw = Kw + (size_t)rows*DM;
    unsigned short* s1u = (unsigned short*)(Vw + (size_t)rows*DM);  // 8 MB bf16

    hipLaunchKernelGGL(proj_kernel, dim3(rows/4), dim3(256), 0, stream,
                       query, key_, value, Wq, bq, Wk, bk, Wv, bv, Qw, Kw, Vw);
    hipLaunchKernelGGL(s1_kernel, dim3(64, 16), dim3(256), 0, stream,
                       Qw, Kw, s1u);
    hipLaunchKernelGGL(attn_kernel, dim3(rows), dim3(256), 0, stream,
                       edges, mask, rkW1, rkb1, rkW2, rkb2, rvW1, rvb1, rvW2, rvb2,
                       vvec, Wo, bo, Qw, Kw, Vw, s1u, (float*)d_out);
}

// Round 8
// 163.046 us; speedup vs baseline: 1.2728x; 1.0105x over previous
//
#include <hip/hip_runtime.h>
#include <hip/hip_bf16.h>

#define HH 8
#define DKK 32
#define DM 256
#define NN 512
#define DE 40
#define DHID 32
#define CH 128
#define NCH 2

typedef __attribute__((ext_vector_type(4))) short short4v;
typedef __attribute__((ext_vector_type(8))) short short8v;
typedef __attribute__((ext_vector_type(4))) float f32x4;

__device__ __forceinline__ unsigned short f2bf(float x) {
    union { __hip_bfloat16 h; unsigned short u; } c;
    c.h = __float2bfloat16(x);
    return c.u;
}
__device__ __forceinline__ float bf2f(unsigned short u) {
    return __uint_as_float(((unsigned int)u) << 16);
}
__device__ __forceinline__ float bf_lo(unsigned int u){ return __uint_as_float(u << 16); }
__device__ __forceinline__ float bf_hi(unsigned int u){ return __uint_as_float(u & 0xffff0000u); }
__device__ __forceinline__ unsigned int pack2bf(float a, float b) {
    return (unsigned int)f2bf(a) | ((unsigned int)f2bf(b) << 16);
}
__device__ __forceinline__ short8v ld8(const unsigned short* p) {
    short4v lo = *(const short4v*)p;
    short4v hi = *(const short4v*)(p + 4);
    short8v r;
    r[0]=lo[0]; r[1]=lo[1]; r[2]=lo[2]; r[3]=lo[3];
    r[4]=hi[0]; r[5]=hi[1]; r[6]=hi[2]; r[7]=hi[3];
    return r;
}

// ---------------- Q/K/V projection: 4 rows per block (row-major) ----------------
__global__ __launch_bounds__(256) void proj_kernel(
    const float* __restrict__ query, const float* __restrict__ key_,
    const float* __restrict__ value,
    const float* __restrict__ Wq, const float* __restrict__ bq,
    const float* __restrict__ Wk, const float* __restrict__ bk,
    const float* __restrict__ Wv, const float* __restrict__ bv,
    float* __restrict__ Q, float* __restrict__ K, float* __restrict__ V)
{
    const int r0 = blockIdx.x * 4;
    const int c = threadIdx.x;
    float aq[4], ak[4], av[4];
    const float bqc = bq[c], bkc = bk[c], bvc = bv[c];
#pragma unroll
    for (int r = 0; r < 4; ++r) { aq[r] = bqc; ak[r] = bkc; av[r] = bvc; }
    for (int k = 0; k < DM; ++k) {
        const float wq = Wq[k*DM + c];
        const float wk = Wk[k*DM + c];
        const float wv = Wv[k*DM + c];
#pragma unroll
        for (int r = 0; r < 4; ++r) {
            aq[r] = fmaf(query[(size_t)(r0+r)*DM + k], wq, aq[r]);   // uniform x
            ak[r] = fmaf(key_ [(size_t)(r0+r)*DM + k], wk, ak[r]);
            av[r] = fmaf(value[(size_t)(r0+r)*DM + k], wv, av[r]);
        }
    }
#pragma unroll
    for (int r = 0; r < 4; ++r) {
        Q[(size_t)(r0+r)*DM + c] = aq[r];
        K[(size_t)(r0+r)*DM + c] = ak[r];
        V[(size_t)(r0+r)*DM + c] = av[r];
    }
}

// ---------------- s1[b,h,i,j] = inv * q_h(i).k_h(j), bf16 out ----------------
__global__ __launch_bounds__(256) void s1_kernel(
    const float* __restrict__ Q, const float* __restrict__ K,
    unsigned short* __restrict__ s1)
{
    const int tid = threadIdx.x;
    const int bh = blockIdx.y, b = bh >> 3, hh = bh & 7;
    const int ti = (blockIdx.x >> 3) * 64, tj = (blockIdx.x & 7) * 64;
    __shared__ float Qt[64][33];
    __shared__ float Kt[64][33];
    const int c = tid & 31, r0 = tid >> 5;
#pragma unroll
    for (int s = 0; s < 8; ++s) {
        Qt[r0 + 8*s][c] = Q[(size_t)(b*NN + ti + r0 + 8*s)*DM + hh*DKK + c];
        Kt[r0 + 8*s][c] = K[(size_t)(b*NN + tj + r0 + 8*s)*DM + hh*DKK + c];
    }
    __syncthreads();
    const int tx = tid & 15, ty = tid >> 4;
    float acc[4][4] = {};
#pragma unroll
    for (int k = 0; k < DKK; ++k) {
        float qv[4], kv[4];
#pragma unroll
        for (int u = 0; u < 4; ++u) { qv[u] = Qt[ty*4+u][k]; kv[u] = Kt[tx*4+u][k]; }
#pragma unroll
        for (int ri = 0; ri < 4; ++ri)
#pragma unroll
            for (int cj = 0; cj < 4; ++cj)
                acc[ri][cj] = fmaf(qv[ri], kv[cj], acc[ri][cj]);
    }
    const float inv = 0.17677669529663687f;
#pragma unroll
    for (int ri = 0; ri < 4; ++ri) {
        ushort4 o;
        o.x = f2bf(acc[ri][0]*inv); o.y = f2bf(acc[ri][1]*inv);
        o.z = f2bf(acc[ri][2]*inv); o.w = f2bf(acc[ri][3]*inv);
        *(ushort4*)(s1 + ((size_t)(b*HH + hh)*NN + ti + ty*4 + ri)*NN + tj + tx*4) = o;
    }
}

// ---------------- chunk kernel: one block per (row i, 256-j half) ----------------
// 2 inner chunks of 128 j, online softmax; MLP layer-1 and accA via MFMA.
__global__ __launch_bounds__(256) void chunk_kernel(
    const float* __restrict__ edges, const int* __restrict__ mask,
    const float* __restrict__ rkW1, const float* __restrict__ rkb1,
    const float* __restrict__ rkW2, const float* __restrict__ rkb2,
    const float* __restrict__ rvW1, const float* __restrict__ rvb1,
    const float* __restrict__ vvec,
    const float* __restrict__ Q, const float* __restrict__ K, const float* __restrict__ V,
    const unsigned short* __restrict__ s1u,
    float* __restrict__ ws_m, float* __restrict__ ws_z,
    float* __restrict__ ws_A, float* __restrict__ ws_O)
{
    const int bid = blockIdx.x;
    const int bi = bid >> 1, cc = bid & 1;   // row, j-half
    const int b  = bi >> 9;
    const int i  = bi & 511;
    const int tid = threadIdx.x;
    const int h = tid >> 5, l32 = tid & 31;          // softmax mapping
    const int wid = tid >> 6, lane = tid & 63;       // wave mapping (mfma)
    const int g = lane >> 4, q16 = lane & 15;
    const int team = tid >> 6, qq = tid & 63, hq = qq >> 3;  // accO mapping
    const int jj = tid & 127, half = tid >> 7;       // E-load / scores mapping
    const float inv = 0.17677669529663687f;

    // ---- LDS: unioned region + persistent buffers ----
    __shared__ __align__(16) unsigned char uni[17408];
    __shared__ __align__(16) unsigned short W1bf[64*68];     // [n=64][k=68], k 40..67 zero
    __shared__ __align__(16) float sc[HH*132];
    __shared__ __align__(16) float gKs[HH*DKK];
    __shared__ float c0Ks[HH], scl_s[HH];

    unsigned short* E   = (unsigned short*)uni;              // [128][68] bf16
    unsigned short* hvT = (unsigned short*)uni;              // [32][132] bf16 (overlays E)
    unsigned short* hk  = (unsigned short*)(uni + 8448);     // [128][34] bf16
    unsigned short* pb  = (unsigned short*)(uni + 8448);     // [16][132] bf16 (in hk space)
    float* wf    = (float*)uni;                              // prologue only
    float* paccA = (float*)uni;                              // [4][256] epilogue
    float* po    = (float*)(uni + 4096);                     // [4][256] epilogue

    const size_t ebase = (size_t)b*DE*NN*NN + (size_t)i*NN;
    const float* qrow = Q + (size_t)bi*DM;

    // ---- prologue: wf, W1bf (combined W1k|W1v bf16, K-padded), bias regs ----
    wf[tid] = inv*(qrow[tid] + K[(size_t)bi*DM + tid]) + vvec[tid];
    {
        const int n = tid >> 2, qd = tid & 3;
#pragma unroll
        for (int kk = 0; kk < 17; ++kk) {
            const int k = qd*17 + kk;
            float v = 0.f;
            if (k < DE) v = (n < 32) ? rkW1[k*DHID + n] : rvW1[k*DHID + (n-32)];
            W1bf[n*68 + k] = f2bf(v);
        }
    }
    float biasv[4];
#pragma unroll
    for (int nt = 0; nt < 4; ++nt) {
        const int n = nt*16 + q16;
        biasv[nt] = (n < 32) ? rkb1[n] : rvb1[n-32];
    }
    __syncthreads();

    // ---- gK[h,t] = rkW2[t, h*32:].w[h,:]; c0K[h] = rkb2[h,:].w[h,:] ----
    {
        float acc = 0.f;
#pragma unroll
        for (int d4 = 0; d4 < DKK/4; ++d4) {
            const float4 w4 = *(const float4*)(rkW2 + (size_t)l32*DM + h*DKK + d4*4);
            const float4 f4 = *(const float4*)(&wf[h*DKK + d4*4]);
            acc = fmaf(w4.x, f4.x, acc); acc = fmaf(w4.y, f4.y, acc);
            acc = fmaf(w4.z, f4.z, acc); acc = fmaf(w4.w, f4.w, acc);
        }
        gKs[h*DKK + l32] = acc;
        if (tid < HH) {
            float a2 = 0.f;
#pragma unroll
            for (int d = 0; d < DKK; ++d)
                a2 = fmaf(rkb2[tid*DKK + d], wf[tid*DKK + d], a2);
            c0Ks[tid] = a2;
        }
    }
    __syncthreads();   // wf dead; E region free

    float m_run = -3e38f, Zacc = 0.f;
    float aO0 = 0.f, aO1 = 0.f, aO2 = 0.f, aO3 = 0.f;
    f32x4 accAf0 = {0.f,0.f,0.f,0.f}, accAf1 = {0.f,0.f,0.f,0.f};
    const float* vb = V + (size_t)b*NN*DM;
    const unsigned short* s1b = s1u + (size_t)b*HH*NN*NN + (size_t)i*NN;

#pragma unroll 1
    for (int ch = 0; ch < NCH; ++ch) {
        const int j0 = cc*256 + ch*CH;

        // ---- E stage: edges -> bf16 LDS [128][68] (cols 40..63 zero) ----
        {
            const float* ep = edges + ebase + j0 + jj;
            float ev[20];
#pragma unroll
            for (int u = 0; u < 20; ++u) ev[u] = ep[(size_t)(half*20+u)*NN*NN];
            unsigned int* Ed = (unsigned int*)&E[jj*68 + half*20];
#pragma unroll
            for (int u = 0; u < 10; ++u) Ed[u] = pack2bf(ev[2*u], ev[2*u+1]);
            if (half) {
                unsigned int* Ez = (unsigned int*)&E[jj*68 + 40];
#pragma unroll
                for (int z = 0; z < 12; ++z) Ez[z] = 0u;
            }
        }
        __syncthreads();

        // ---- h1 = E @ W1 (+bias) via MFMA: wave owns 32 j rows ----
        f32x4 acc[2][4];
        {
            short8v bk0[4], bk1[4];
#pragma unroll
            for (int nt = 0; nt < 4; ++nt) {
                const unsigned short* wp = &W1bf[(q16 + nt*16)*68 + g*8];
                bk0[nt] = ld8(wp);
                bk1[nt] = ld8(wp + 32);
            }
#pragma unroll
            for (int jt = 0; jt < 2; ++jt) {
                const int jn = wid*32 + jt*16 + q16;
                short8v a0 = ld8(&E[jn*68 + g*8]);
                short8v a1 = ld8(&E[jn*68 + 32 + g*8]);
#pragma unroll
                for (int nt = 0; nt < 4; ++nt) {
                    f32x4 c;
                    c[0] = biasv[nt]; c[1] = biasv[nt]; c[2] = biasv[nt]; c[3] = biasv[nt];
                    c = __builtin_amdgcn_mfma_f32_16x16x32_bf16(a0, bk0[nt], c, 0, 0, 0);
                    c = __builtin_amdgcn_mfma_f32_16x16x32_bf16(a1, bk1[nt], c, 0, 0, 0);
                    acc[jt][nt] = c;
                }
            }
        }
        __syncthreads();   // all E reads done before overwrite

        // ---- leaky + writeback: hk[j][t] and hvT[t][j] ----
#pragma unroll
        for (int jt = 0; jt < 2; ++jt) {
            const int jw = wid*32 + jt*16 + g*4;
#pragma unroll
            for (int nt = 0; nt < 4; ++nt) {
#pragma unroll
                for (int r = 0; r < 4; ++r) {
                    float x = acc[jt][nt][r];
                    x = x > 0.f ? x : 0.1f*x;
                    const unsigned short us = f2bf(x);
                    const int n = nt*16 + q16;
                    if (n < 32) hk[(jw+r)*34 + n] = us;
                    else        hvT[(n-32)*132 + (jw+r)] = us;
                }
            }
        }
        __syncthreads();   // hk/hvT ready

        // ---- scores: s2 (gK . h1k) + s1 + mask ----
        {
            unsigned int hku[16];
#pragma unroll
            for (int d = 0; d < 16; ++d) hku[d] = *(const unsigned int*)&hk[jj*34 + 2*d];
            const int mk = mask[b*NN + j0 + jj];
            float racc[4];
#pragma unroll
            for (int u = 0; u < 4; ++u) racc[u] = c0Ks[half*4 + u];
#pragma unroll
            for (int d = 0; d < 16; ++d) {
                const float lo = bf_lo(hku[d]), hi = bf_hi(hku[d]);
#pragma unroll
                for (int u = 0; u < 4; ++u) {
                    const int hh = half*4 + u;
                    racc[u] = fmaf(gKs[hh*DKK + 2*d],     lo, racc[u]);
                    racc[u] = fmaf(gKs[hh*DKK + 2*d + 1], hi, racc[u]);
                }
            }
#pragma unroll
            for (int u = 0; u < 4; ++u) {
                const int hh = half*4 + u;
                float r = racc[u] + bf2f(s1b[(size_t)hh*NN*NN + j0 + jj]);
                if (mk == 0) r = -1e12f;
                sc[hh*132 + jj] = r;
            }
        }
        __syncthreads();

        // ---- online softmax (head h per 32-lane group), publish p bf16 + scl ----
        {
            float sv[4];
            float mc = -3e38f;
#pragma unroll
            for (int k = 0; k < 4; ++k) { sv[k] = sc[h*132 + l32 + 32*k]; mc = fmaxf(mc, sv[k]); }
#pragma unroll
            for (int off = 16; off; off >>= 1) mc = fmaxf(mc, __shfl_xor(mc, off, 32));
            const float mnew = fmaxf(m_run, mc);
            const float scl = __expf(m_run - mnew);
            m_run = mnew;
            Zacc *= scl;
            float zc = 0.f;
#pragma unroll
            for (int k = 0; k < 4; ++k) {
                const float e = __expf(sv[k] - m_run);
                pb[h*132 + l32 + 32*k] = f2bf(e);
                zc += e;
            }
#pragma unroll
            for (int off = 16; off; off >>= 1) zc += __shfl_xor(zc, off, 32);
            Zacc += zc;
            if (l32 == 0) scl_s[h] = scl;
        }
        __syncthreads();   // pb + scl_s visible

        // ---- rescale + accA via MFMA (p[16x128] @ h1v[128x32], wave = K-quarter) ----
        {
            const float s0 = scl_s[(g*4+0)&7], s1r = scl_s[(g*4+1)&7];
            const float s2r = scl_s[(g*4+2)&7], s3r = scl_s[(g*4+3)&7];
            accAf0[0]*=s0; accAf0[1]*=s1r; accAf0[2]*=s2r; accAf0[3]*=s3r;
            accAf1[0]*=s0; accAf1[1]*=s1r; accAf1[2]*=s2r; accAf1[3]*=s3r;
            short8v pA = ld8(&pb[q16*132 + wid*32 + g*8]);
            short8v b0 = ld8(&hvT[q16*132 + wid*32 + g*8]);
            short8v b1 = ld8(&hvT[(16+q16)*132 + wid*32 + g*8]);
            accAf0 = __builtin_amdgcn_mfma_f32_16x16x32_bf16(pA, b0, accAf0, 0, 0, 0);
            accAf1 = __builtin_amdgcn_mfma_f32_16x16x32_bf16(pA, b1, accAf1, 0, 0, 0);

            // ---- accO: channels qq*4..+3, j = j0 + team + 4*it ----
            const float sO = scl_s[hq];
            aO0 *= sO; aO1 *= sO; aO2 *= sO; aO3 *= sO;
            const float* vrow = vb + (size_t)(j0 + team)*DM + qq*4;
            const unsigned short* ph = pb + hq*132 + team;
#pragma unroll 4
            for (int it = 0; it < 32; ++it) {
                const float p = bf2f(ph[4*it]);
                const float4 v4 = *(const float4*)(vrow + (size_t)it*4*DM);
                aO0 = fmaf(p, v4.x, aO0); aO1 = fmaf(p, v4.y, aO1);
                aO2 = fmaf(p, v4.z, aO2); aO3 = fmaf(p, v4.w, aO3);
            }
        }
        __syncthreads();   // chunk consumed; next E overwrite safe
    }

    // ---- epilogue: reduce wave partials, emit raw (m, Z, A, O) ----
    if (g < 2) {
#pragma unroll
        for (int r = 0; r < 4; ++r) {
            paccA[wid*256 + (4*g+r)*32 + q16]      = accAf0[r];
            paccA[wid*256 + (4*g+r)*32 + 16 + q16] = accAf1[r];
        }
    }
    *(float4*)(po + team*256 + qq*4) = make_float4(aO0, aO1, aO2, aO3);
    __syncthreads();

    ws_A[(size_t)bid*256 + tid] = paccA[tid] + paccA[256+tid] + paccA[512+tid] + paccA[768+tid];
    ws_O[(size_t)bid*256 + tid] = po[tid] + po[256+tid] + po[512+tid] + po[768+tid];
    if (l32 == 0) {
        ws_m[(size_t)bid*8 + h] = m_run;
        ws_z[(size_t)bid*8 + h] = Zacc;
    }
}

// ---------------- combine: 2-way flash merge, o2, Wo epilogue. one block per row ----------------
__global__ __launch_bounds__(256) void combine_kernel(
    const float* __restrict__ rvW2, const float* __restrict__ rvb2,
    const float* __restrict__ Wo, const float* __restrict__ bo,
    const float* __restrict__ ws_m, const float* __restrict__ ws_z,
    const float* __restrict__ ws_A, const float* __restrict__ ws_O,
    float* __restrict__ out)
{
    const int bi = blockIdx.x;
    const int tid = threadIdx.x;
    const int h = tid >> 5;
    __shared__ float A_l[DM], o_l[DM];
    __shared__ float w0s[HH], w1s[HH], rzs[HH];

    if (tid < HH) {
        const float m0 = ws_m[(size_t)(bi*2+0)*8 + tid];
        const float m1 = ws_m[(size_t)(bi*2+1)*8 + tid];
        const float z0 = ws_z[(size_t)(bi*2+0)*8 + tid];
        const float z1 = ws_z[(size_t)(bi*2+1)*8 + tid];
        const float mm = fmaxf(m0, m1);
        const float w0 = __expf(m0 - mm), w1 = __expf(m1 - mm);
        w0s[tid] = w0; w1s[tid] = w1;
        rzs[tid] = 1.f / (z0*w0 + z1*w1);
    }
    __syncthreads();

    const float w0 = w0s[h], w1 = w1s[h], rz = rzs[h];
    A_l[tid] = (w0*ws_A[(size_t)(bi*2)*256 + tid] + w1*ws_A[(size_t)(bi*2+1)*256 + tid]) * rz;
    const float o1 = (w0*ws_O[(size_t)(bi*2)*256 + tid] + w1*ws_O[(size_t)(bi*2+1)*256 + tid]) * rz;
    __syncthreads();

    float o2 = rvb2[tid];
#pragma unroll
    for (int t = 0; t < DHID; ++t)
        o2 = fmaf(A_l[h*DKK + t], rvW2[(size_t)t*DM + tid], o2);
    o_l[tid] = o1 + o2;
    __syncthreads();

    float acc = bo[tid];
#pragma unroll 4
    for (int k = 0; k < DM; ++k)
        acc = fmaf(o_l[k], Wo[(size_t)k*DM + tid], acc);
    out[(size_t)bi*DM + tid] = acc;
}

extern "C" void kernel_launch(void* const* d_in, const int* in_sizes, int n_in,
                              void* d_out, int out_size, void* d_ws, size_t ws_size,
                              hipStream_t stream) {
    const float* query = (const float*)d_in[0];
    const float* key_  = (const float*)d_in[1];
    const float* value = (const float*)d_in[2];
    const float* edges = (const float*)d_in[3];
    const int*   mask  = (const int*)d_in[4];
    const float* Wq = (const float*)d_in[5];
    const float* bq = (const float*)d_in[6];
    const float* Wk = (const float*)d_in[7];
    const float* bk = (const float*)d_in[8];
    const float* Wv = (const float*)d_in[9];
    const float* bv = (const float*)d_in[10];
    const float* Wo = (const float*)d_in[11];
    const float* bo = (const float*)d_in[12];
    const float* rkW1 = (const float*)d_in[13];
    const float* rkb1 = (const float*)d_in[14];
    const float* rkW2 = (const float*)d_in[15];
    const float* rkb2 = (const float*)d_in[16];
    const float* rvW1 = (const float*)d_in[17];
    const float* rvb1 = (const float*)d_in[18];
    const float* rvW2 = (const float*)d_in[19];
    const float* rvb2 = (const float*)d_in[20];
    // d_in[21] (u) is softmax-invariant -> unused
    const float* vvec = (const float*)d_in[22];

    const int rows = in_sizes[0] / DM;   // b*n = 1024
    const int nchunk = rows * 2;         // 2048

    float* Qw = (float*)d_ws;
    float* Kw = Qw + (size_t)rows*DM;
    float* Vw = Kw + (size_t)rows*DM;
    unsigned short* s1u = (unsigned short*)(Vw + (size_t)rows*DM);  // 8.4 MB bf16
    float* ws_m = (float*)(s1u + (size_t)2*HH*NN*NN);
    float* ws_z = ws_m + (size_t)nchunk*8;
    float* ws_A = ws_z + (size_t)nchunk*8;
    float* ws_O = ws_A + (size_t)nchunk*256;

    hipLaunchKernelGGL(proj_kernel, dim3(rows/4), dim3(256), 0, stream,
                       query, key_, value, Wq, bq, Wk, bk, Wv, bv, Qw, Kw, Vw);
    hipLaunchKernelGGL(s1_kernel, dim3(64, 16), dim3(256), 0, stream,
                       Qw, Kw, s1u);
    hipLaunchKernelGGL(chunk_kernel, dim3(nchunk), dim3(256), 0, stream,
                       edges, mask, rkW1, rkb1, rkW2, rkb2, rvW1, rvb1,
                       vvec, Qw, Kw, Vw, s1u, ws_m, ws_z, ws_A, ws_O);
    hipLaunchKernelGGL(combine_kernel, dim3(rows), dim3(256), 0, stream,
                       rvW2, rvb2, Wo, bo, ws_m, ws_z, ws_A, ws_O, (float*)d_out);
}

// Round 9
// 145.513 us; speedup vs baseline: 1.4262x; 1.1205x over previous
//
#include <hip/hip_runtime.h>
#include <hip/hip_bf16.h>

#define HH 8
#define DKK 32
#define DM 256
#define NN 512
#define DE 40
#define DHID 32
#define CH 128
#define NCH 2

typedef __attribute__((ext_vector_type(4))) short short4v;
typedef __attribute__((ext_vector_type(8))) short short8v;
typedef __attribute__((ext_vector_type(4))) float f32x4;

__device__ __forceinline__ unsigned short f2bf(float x) {
    union { __hip_bfloat16 h; unsigned short u; } c;
    c.h = __float2bfloat16(x);
    return c.u;
}
__device__ __forceinline__ float bf2f(unsigned short u) {
    return __uint_as_float(((unsigned int)u) << 16);
}
__device__ __forceinline__ float bf_lo(unsigned int u){ return __uint_as_float(u << 16); }
__device__ __forceinline__ float bf_hi(unsigned int u){ return __uint_as_float(u & 0xffff0000u); }
__device__ __forceinline__ unsigned int pack2bf(float a, float b) {
    return (unsigned int)f2bf(a) | ((unsigned int)f2bf(b) << 16);
}
__device__ __forceinline__ short8v ld8(const unsigned short* p) {
    short4v lo = *(const short4v*)p;
    short4v hi = *(const short4v*)(p + 4);
    short8v r;
    r[0]=lo[0]; r[1]=lo[1]; r[2]=lo[2]; r[3]=lo[3];
    r[4]=hi[0]; r[5]=hi[1]; r[6]=hi[2]; r[7]=hi[3];
    return r;
}

// ---------------- Q/K/V projection: 4 rows per block (row-major) ----------------
__global__ __launch_bounds__(256) void proj_kernel(
    const float* __restrict__ query, const float* __restrict__ key_,
    const float* __restrict__ value,
    const float* __restrict__ Wq, const float* __restrict__ bq,
    const float* __restrict__ Wk, const float* __restrict__ bk,
    const float* __restrict__ Wv, const float* __restrict__ bv,
    float* __restrict__ Q, float* __restrict__ K, float* __restrict__ V)
{
    const int r0 = blockIdx.x * 4;
    const int c = threadIdx.x;
    float aq[4], ak[4], av[4];
    const float bqc = bq[c], bkc = bk[c], bvc = bv[c];
#pragma unroll
    for (int r = 0; r < 4; ++r) { aq[r] = bqc; ak[r] = bkc; av[r] = bvc; }
    for (int k = 0; k < DM; ++k) {
        const float wq = Wq[k*DM + c];
        const float wk = Wk[k*DM + c];
        const float wv = Wv[k*DM + c];
#pragma unroll
        for (int r = 0; r < 4; ++r) {
            aq[r] = fmaf(query[(size_t)(r0+r)*DM + k], wq, aq[r]);   // uniform x
            ak[r] = fmaf(key_ [(size_t)(r0+r)*DM + k], wk, ak[r]);
            av[r] = fmaf(value[(size_t)(r0+r)*DM + k], wv, av[r]);
        }
    }
#pragma unroll
    for (int r = 0; r < 4; ++r) {
        Q[(size_t)(r0+r)*DM + c] = aq[r];
        K[(size_t)(r0+r)*DM + c] = ak[r];
        V[(size_t)(r0+r)*DM + c] = av[r];
    }
}

// ---------------- s1[b,h,i,j] = inv * q_h(i).k_h(j), bf16 out ----------------
__global__ __launch_bounds__(256) void s1_kernel(
    const float* __restrict__ Q, const float* __restrict__ K,
    unsigned short* __restrict__ s1)
{
    const int tid = threadIdx.x;
    const int bh = blockIdx.y, b = bh >> 3, hh = bh & 7;
    const int ti = (blockIdx.x >> 3) * 64, tj = (blockIdx.x & 7) * 64;
    __shared__ float Qt[64][33];
    __shared__ float Kt[64][33];
    const int c = tid & 31, r0 = tid >> 5;
#pragma unroll
    for (int s = 0; s < 8; ++s) {
        Qt[r0 + 8*s][c] = Q[(size_t)(b*NN + ti + r0 + 8*s)*DM + hh*DKK + c];
        Kt[r0 + 8*s][c] = K[(size_t)(b*NN + tj + r0 + 8*s)*DM + hh*DKK + c];
    }
    __syncthreads();
    const int tx = tid & 15, ty = tid >> 4;
    float acc[4][4] = {};
#pragma unroll
    for (int k = 0; k < DKK; ++k) {
        float qv[4], kv[4];
#pragma unroll
        for (int u = 0; u < 4; ++u) { qv[u] = Qt[ty*4+u][k]; kv[u] = Kt[tx*4+u][k]; }
#pragma unroll
        for (int ri = 0; ri < 4; ++ri)
#pragma unroll
            for (int cj = 0; cj < 4; ++cj)
                acc[ri][cj] = fmaf(qv[ri], kv[cj], acc[ri][cj]);
    }
    const float inv = 0.17677669529663687f;
#pragma unroll
    for (int ri = 0; ri < 4; ++ri) {
        ushort4 o;
        o.x = f2bf(acc[ri][0]*inv); o.y = f2bf(acc[ri][1]*inv);
        o.z = f2bf(acc[ri][2]*inv); o.w = f2bf(acc[ri][3]*inv);
        *(ushort4*)(s1 + ((size_t)(b*HH + hh)*NN + ti + ty*4 + ri)*NN + tj + tx*4) = o;
    }
}

// ---------------- chunk kernel: one block per (row i, 256-j half) ----------------
// 2 inner chunks of 128 j, online softmax; MLP layer-1 and accA via MFMA.
// __launch_bounds__(256,4): force combined VGPR+AGPR <= 128 -> 4 waves/SIMD.
__global__ __launch_bounds__(256, 4) void chunk_kernel(
    const float* __restrict__ edges, const int* __restrict__ mask,
    const float* __restrict__ rkW1, const float* __restrict__ rkb1,
    const float* __restrict__ rkW2, const float* __restrict__ rkb2,
    const float* __restrict__ rvW1, const float* __restrict__ rvb1,
    const float* __restrict__ vvec,
    const float* __restrict__ Q, const float* __restrict__ K, const float* __restrict__ V,
    const unsigned short* __restrict__ s1u,
    float* __restrict__ ws_m, float* __restrict__ ws_z,
    float* __restrict__ ws_A, float* __restrict__ ws_O)
{
    const int bid = blockIdx.x;
    const int bi = bid >> 1, cc = bid & 1;   // row, j-half
    const int b  = bi >> 9;
    const int i  = bi & 511;
    const int tid = threadIdx.x;
    const int h = tid >> 5, l32 = tid & 31;          // softmax mapping
    const int wid = tid >> 6, lane = tid & 63;       // wave mapping (mfma)
    const int g = lane >> 4, q16 = lane & 15;
    const int team = tid >> 6, qq = tid & 63, hq = qq >> 3;  // accO mapping
    const int jj = tid & 127, half = tid >> 7;       // E-load / scores mapping
    const float inv = 0.17677669529663687f;

    // ---- LDS: unioned region + persistent buffers ----
    __shared__ __align__(16) unsigned char uni[17408];
    __shared__ __align__(16) unsigned short W1bf[64*68];     // [n=64][k=68], k 40..67 zero
    __shared__ __align__(16) float sc[HH*132];
    __shared__ __align__(16) float gKs[HH*DKK];
    __shared__ float c0Ks[HH], scl_s[HH];

    unsigned short* E   = (unsigned short*)uni;              // [128][68] bf16
    unsigned short* hvT = (unsigned short*)uni;              // [32][132] bf16 (overlays E)
    unsigned short* hk  = (unsigned short*)(uni + 8448);     // [128][34] bf16
    unsigned short* pb  = (unsigned short*)(uni + 8448);     // [16][132] bf16 (in hk space)
    float* wf    = (float*)uni;                              // prologue only
    float* paccA = (float*)uni;                              // [4][256] epilogue
    float* po    = (float*)(uni + 4096);                     // [4][256] epilogue

    const size_t ebase = (size_t)b*DE*NN*NN + (size_t)i*NN;
    const float* qrow = Q + (size_t)bi*DM;

    // ---- prefetch chunk 0 edges into regs (completes under prologue) ----
    float ev[NCH][20];
    {
        const float* ep = edges + ebase + cc*256 + jj;
#pragma unroll
        for (int u = 0; u < 20; ++u) ev[0][u] = ep[(size_t)(half*20+u)*NN*NN];
    }

    // ---- prologue: wf, W1bf (combined W1k|W1v bf16, K-padded), bias regs ----
    wf[tid] = inv*(qrow[tid] + K[(size_t)bi*DM + tid]) + vvec[tid];
    {
        const int n = tid >> 2, qd = tid & 3;
#pragma unroll
        for (int kk = 0; kk < 17; ++kk) {
            const int k = qd*17 + kk;
            float v = 0.f;
            if (k < DE) v = (n < 32) ? rkW1[k*DHID + n] : rvW1[k*DHID + (n-32)];
            W1bf[n*68 + k] = f2bf(v);
        }
    }
    float biasv[4];
#pragma unroll
    for (int nt = 0; nt < 4; ++nt) {
        const int n = nt*16 + q16;
        biasv[nt] = (n < 32) ? rkb1[n] : rvb1[n-32];
    }
    __syncthreads();

    // ---- gK[h,t] = rkW2[t, h*32:].w[h,:]; c0K[h] = rkb2[h,:].w[h,:] ----
    {
        float acc = 0.f;
#pragma unroll
        for (int d4 = 0; d4 < DKK/4; ++d4) {
            const float4 w4 = *(const float4*)(rkW2 + (size_t)l32*DM + h*DKK + d4*4);
            const float4 f4 = *(const float4*)(&wf[h*DKK + d4*4]);
            acc = fmaf(w4.x, f4.x, acc); acc = fmaf(w4.y, f4.y, acc);
            acc = fmaf(w4.z, f4.z, acc); acc = fmaf(w4.w, f4.w, acc);
        }
        gKs[h*DKK + l32] = acc;
        if (tid < HH) {
            float a2 = 0.f;
#pragma unroll
            for (int d = 0; d < DKK; ++d)
                a2 = fmaf(rkb2[tid*DKK + d], wf[tid*DKK + d], a2);
            c0Ks[tid] = a2;
        }
    }
    __syncthreads();   // wf dead; E region free

    float m_run = -3e38f, Zacc = 0.f;
    float aO0 = 0.f, aO1 = 0.f, aO2 = 0.f, aO3 = 0.f;
    f32x4 accAf0 = {0.f,0.f,0.f,0.f}, accAf1 = {0.f,0.f,0.f,0.f};
    const float* vb = V + (size_t)b*NN*DM;
    const unsigned short* s1b = s1u + (size_t)b*HH*NN*NN + (size_t)i*NN;

#pragma unroll
    for (int ch = 0; ch < NCH; ++ch) {
        const int j0 = cc*256 + ch*CH;

        // ---- pack prefetched edges -> bf16 LDS [128][68] (cols 40..63 zero) ----
        {
            unsigned int* Ed = (unsigned int*)&E[jj*68 + half*20];
#pragma unroll
            for (int u = 0; u < 10; ++u) Ed[u] = pack2bf(ev[ch][2*u], ev[ch][2*u+1]);
            if (half) {
                unsigned int* Ez = (unsigned int*)&E[jj*68 + 40];
#pragma unroll
                for (int z = 0; z < 12; ++z) Ez[z] = 0u;
            }
        }
        // ---- T14: issue next chunk's edge loads now; they land under this chunk's compute ----
        if (ch + 1 < NCH) {
            const float* ep = edges + ebase + cc*256 + (ch+1)*CH + jj;
#pragma unroll
            for (int u = 0; u < 20; ++u) ev[ch+1][u] = ep[(size_t)(half*20+u)*NN*NN];
        }
        __syncthreads();   // E ready

        // ---- h1 = E @ W1 (+bias) via MFMA: wave owns 32 j rows ----
        f32x4 acc[2][4];
#pragma unroll
        for (int jt = 0; jt < 2; ++jt) {
            const int jn = wid*32 + jt*16 + q16;
            short8v a0 = ld8(&E[jn*68 + g*8]);
            short8v a1 = ld8(&E[jn*68 + 32 + g*8]);
#pragma unroll
            for (int nt = 0; nt < 4; ++nt) {
                const unsigned short* wp = &W1bf[(q16 + nt*16)*68 + g*8];
                f32x4 c;
                c[0] = biasv[nt]; c[1] = biasv[nt]; c[2] = biasv[nt]; c[3] = biasv[nt];
                c = __builtin_amdgcn_mfma_f32_16x16x32_bf16(a0, ld8(wp), c, 0, 0, 0);
                c = __builtin_amdgcn_mfma_f32_16x16x32_bf16(a1, ld8(wp + 32), c, 0, 0, 0);
                acc[jt][nt] = c;
            }
        }
        __syncthreads();   // all E reads done before overwrite

        // ---- leaky + writeback: hk[j][t] and hvT[t][j] ----
#pragma unroll
        for (int jt = 0; jt < 2; ++jt) {
            const int jw = wid*32 + jt*16 + g*4;
#pragma unroll
            for (int nt = 0; nt < 4; ++nt) {
#pragma unroll
                for (int r = 0; r < 4; ++r) {
                    float x = acc[jt][nt][r];
                    x = x > 0.f ? x : 0.1f*x;
                    const unsigned short us = f2bf(x);
                    const int n = nt*16 + q16;
                    if (n < 32) hk[(jw+r)*34 + n] = us;
                    else        hvT[(n-32)*132 + (jw+r)] = us;
                }
            }
        }
        __syncthreads();   // hk/hvT ready

        // ---- scores: s2 (gK . h1k) + s1 + mask ----
        {
            unsigned int hku[16];
#pragma unroll
            for (int d = 0; d < 16; ++d) hku[d] = *(const unsigned int*)&hk[jj*34 + 2*d];
            const int mk = mask[b*NN + j0 + jj];
            float racc[4];
#pragma unroll
            for (int u = 0; u < 4; ++u) racc[u] = c0Ks[half*4 + u];
#pragma unroll
            for (int d = 0; d < 16; ++d) {
                const float lo = bf_lo(hku[d]), hi = bf_hi(hku[d]);
#pragma unroll
                for (int u = 0; u < 4; ++u) {
                    const int hh = half*4 + u;
                    racc[u] = fmaf(gKs[hh*DKK + 2*d],     lo, racc[u]);
                    racc[u] = fmaf(gKs[hh*DKK + 2*d + 1], hi, racc[u]);
                }
            }
#pragma unroll
            for (int u = 0; u < 4; ++u) {
                const int hh = half*4 + u;
                float r = racc[u] + bf2f(s1b[(size_t)hh*NN*NN + j0 + jj]);
                if (mk == 0) r = -1e12f;
                sc[hh*132 + jj] = r;
            }
        }
        __syncthreads();

        // ---- online softmax (head h per 32-lane group), publish p bf16 + scl ----
        {
            float sv[4];
            float mc = -3e38f;
#pragma unroll
            for (int k = 0; k < 4; ++k) { sv[k] = sc[h*132 + l32 + 32*k]; mc = fmaxf(mc, sv[k]); }
#pragma unroll
            for (int off = 16; off; off >>= 1) mc = fmaxf(mc, __shfl_xor(mc, off, 32));
            const float mnew = fmaxf(m_run, mc);
            const float scl = __expf(m_run - mnew);
            m_run = mnew;
            Zacc *= scl;
            float zc = 0.f;
#pragma unroll
            for (int k = 0; k < 4; ++k) {
                const float e = __expf(sv[k] - m_run);
                pb[h*132 + l32 + 32*k] = f2bf(e);
                zc += e;
            }
#pragma unroll
            for (int off = 16; off; off >>= 1) zc += __shfl_xor(zc, off, 32);
            Zacc += zc;
            if (l32 == 0) scl_s[h] = scl;
        }
        __syncthreads();   // pb + scl_s visible

        // ---- rescale + accA via MFMA (p[16x128] @ h1v[128x32], wave = K-quarter) ----
        {
            const float s0 = scl_s[(g*4+0)&7], s1r = scl_s[(g*4+1)&7];
            const float s2r = scl_s[(g*4+2)&7], s3r = scl_s[(g*4+3)&7];
            accAf0[0]*=s0; accAf0[1]*=s1r; accAf0[2]*=s2r; accAf0[3]*=s3r;
            accAf1[0]*=s0; accAf1[1]*=s1r; accAf1[2]*=s2r; accAf1[3]*=s3r;
            short8v pA = ld8(&pb[q16*132 + wid*32 + g*8]);
            short8v b0 = ld8(&hvT[q16*132 + wid*32 + g*8]);
            short8v b1 = ld8(&hvT[(16+q16)*132 + wid*32 + g*8]);
            accAf0 = __builtin_amdgcn_mfma_f32_16x16x32_bf16(pA, b0, accAf0, 0, 0, 0);
            accAf1 = __builtin_amdgcn_mfma_f32_16x16x32_bf16(pA, b1, accAf1, 0, 0, 0);

            // ---- accO: channels qq*4..+3, j = j0 + team + 4*it ----
            const float sO = scl_s[hq];
            aO0 *= sO; aO1 *= sO; aO2 *= sO; aO3 *= sO;
            const float* vrow = vb + (size_t)(j0 + team)*DM + qq*4;
            const unsigned short* ph = pb + hq*132 + team;
#pragma unroll 4
            for (int it = 0; it < 32; ++it) {
                const float p = bf2f(ph[4*it]);
                const float4 v4 = *(const float4*)(vrow + (size_t)it*4*DM);
                aO0 = fmaf(p, v4.x, aO0); aO1 = fmaf(p, v4.y, aO1);
                aO2 = fmaf(p, v4.z, aO2); aO3 = fmaf(p, v4.w, aO3);
            }
        }
        __syncthreads();   // chunk consumed; next E overwrite safe
    }

    // ---- epilogue: reduce wave partials, emit raw (m, Z, A, O) ----
    if (g < 2) {
#pragma unroll
        for (int r = 0; r < 4; ++r) {
            paccA[wid*256 + (4*g+r)*32 + q16]      = accAf0[r];
            paccA[wid*256 + (4*g+r)*32 + 16 + q16] = accAf1[r];
        }
    }
    *(float4*)(po + team*256 + qq*4) = make_float4(aO0, aO1, aO2, aO3);
    __syncthreads();

    ws_A[(size_t)bid*256 + tid] = paccA[tid] + paccA[256+tid] + paccA[512+tid] + paccA[768+tid];
    ws_O[(size_t)bid*256 + tid] = po[tid] + po[256+tid] + po[512+tid] + po[768+tid];
    if (l32 == 0) {
        ws_m[(size_t)bid*8 + h] = m_run;
        ws_z[(size_t)bid*8 + h] = Zacc;
    }
}

// ---------------- combine: 2-way flash merge, o2, Wo epilogue. one block per row ----------------
__global__ __launch_bounds__(256) void combine_kernel(
    const float* __restrict__ rvW2, const float* __restrict__ rvb2,
    const float* __restrict__ Wo, const float* __restrict__ bo,
    const float* __restrict__ ws_m, const float* __restrict__ ws_z,
    const float* __restrict__ ws_A, const float* __restrict__ ws_O,
    float* __restrict__ out)
{
    const int bi = blockIdx.x;
    const int tid = threadIdx.x;
    const int h = tid >> 5;
    __shared__ float A_l[DM], o_l[DM];
    __shared__ float w0s[HH], w1s[HH], rzs[HH];

    if (tid < HH) {
        const float m0 = ws_m[(size_t)(bi*2+0)*8 + tid];
        const float m1 = ws_m[(size_t)(bi*2+1)*8 + tid];
        const float z0 = ws_z[(size_t)(bi*2+0)*8 + tid];
        const float z1 = ws_z[(size_t)(bi*2+1)*8 + tid];
        const float mm = fmaxf(m0, m1);
        const float w0 = __expf(m0 - mm), w1 = __expf(m1 - mm);
        w0s[tid] = w0; w1s[tid] = w1;
        rzs[tid] = 1.f / (z0*w0 + z1*w1);
    }
    __syncthreads();

    const float w0 = w0s[h], w1 = w1s[h], rz = rzs[h];
    A_l[tid] = (w0*ws_A[(size_t)(bi*2)*256 + tid] + w1*ws_A[(size_t)(bi*2+1)*256 + tid]) * rz;
    const float o1 = (w0*ws_O[(size_t)(bi*2)*256 + tid] + w1*ws_O[(size_t)(bi*2+1)*256 + tid]) * rz;
    __syncthreads();

    float o2 = rvb2[tid];
#pragma unroll
    for (int t = 0; t < DHID; ++t)
        o2 = fmaf(A_l[h*DKK + t], rvW2[(size_t)t*DM + tid], o2);
    o_l[tid] = o1 + o2;
    __syncthreads();

    float acc = bo[tid];
#pragma unroll 4
    for (int k = 0; k < DM; ++k)
        acc = fmaf(o_l[k], Wo[(size_t)k*DM + tid], acc);
    out[(size_t)bi*DM + tid] = acc;
}

extern "C" void kernel_launch(void* const* d_in, const int* in_sizes, int n_in,
                              void* d_out, int out_size, void* d_ws, size_t ws_size,
                              hipStream_t stream) {
    const float* query = (const float*)d_in[0];
    const float* key_  = (const float*)d_in[1];
    const float* value = (const float*)d_in[2];
    const float* edges = (const float*)d_in[3];
    const int*   mask  = (const int*)d_in[4];
    const float* Wq = (const float*)d_in[5];
    const float* bq = (const float*)d_in[6];
    const float* Wk = (const float*)d_in[7];
    const float* bk = (const float*)d_in[8];
    const float* Wv = (const float*)d_in[9];
    const float* bv = (const float*)d_in[10];
    const float* Wo = (const float*)d_in[11];
    const float* bo = (const float*)d_in[12];
    const float* rkW1 = (const float*)d_in[13];
    const float* rkb1 = (const float*)d_in[14];
    const float* rkW2 = (const float*)d_in[15];
    const float* rkb2 = (const float*)d_in[16];
    const float* rvW1 = (const float*)d_in[17];
    const float* rvb1 = (const float*)d_in[18];
    const float* rvW2 = (const float*)d_in[19];
    const float* rvb2 = (const float*)d_in[20];
    // d_in[21] (u) is softmax-invariant -> unused
    const float* vvec = (const float*)d_in[22];

    const int rows = in_sizes[0] / DM;   // b*n = 1024
    const int nchunk = rows * 2;         // 2048

    float* Qw = (float*)d_ws;
    float* Kw = Qw + (size_t)rows*DM;
    float* Vw = Kw + (size_t)rows*DM;
    unsigned short* s1u = (unsigned short*)(Vw + (size_t)rows*DM);  // 8.4 MB bf16
    float* ws_m = (float*)(s1u + (size_t)2*HH*NN*NN);
    float* ws_z = ws_m + (size_t)nchunk*8;
    float* ws_A = ws_z + (size_t)nchunk*8;
    float* ws_O = ws_A + (size_t)nchunk*256;

    hipLaunchKernelGGL(proj_kernel, dim3(rows/4), dim3(256), 0, stream,
                       query, key_, value, Wq, bq, Wk, bk, Wv, bv, Qw, Kw, Vw);
    hipLaunchKernelGGL(s1_kernel, dim3(64, 16), dim3(256), 0, stream,
                       Qw, Kw, s1u);
    hipLaunchKernelGGL(chunk_kernel, dim3(nchunk), dim3(256), 0, stream,
                       edges, mask, rkW1, rkb1, rkW2, rkb2, rvW1, rvb1,
                       vvec, Qw, Kw, Vw, s1u, ws_m, ws_z, ws_A, ws_O);
    hipLaunchKernelGGL(combine_kernel, dim3(rows), dim3(256), 0, stream,
                       rvW2, rvb2, Wo, bo, ws_m, ws_z, ws_A, ws_O, (float*)d_out);
}

// Round 10
// 115.636 us; speedup vs baseline: 1.7947x; 1.2584x over previous
//
#include <hip/hip_runtime.h>
#include <hip/hip_bf16.h>

#define HH 8
#define DKK 32
#define DM 256
#define NN 512
#define DE 40
#define DHID 32
#define CH 128

typedef __attribute__((ext_vector_type(4))) short short4v;
typedef __attribute__((ext_vector_type(8))) short short8v;
typedef __attribute__((ext_vector_type(4))) float f32x4;

__device__ __forceinline__ unsigned short f2bf(float x) {
    union { __hip_bfloat16 h; unsigned short u; } c;
    c.h = __float2bfloat16(x);
    return c.u;
}
__device__ __forceinline__ float bf2f(unsigned short u) {
    return __uint_as_float(((unsigned int)u) << 16);
}
__device__ __forceinline__ float bf_lo(unsigned int u){ return __uint_as_float(u << 16); }
__device__ __forceinline__ float bf_hi(unsigned int u){ return __uint_as_float(u & 0xffff0000u); }
__device__ __forceinline__ unsigned int pack2bf(float a, float b) {
    return (unsigned int)f2bf(a) | ((unsigned int)f2bf(b) << 16);
}
__device__ __forceinline__ short8v ld8(const unsigned short* p) {
    short4v lo = *(const short4v*)p;
    short4v hi = *(const short4v*)(p + 4);
    short8v r;
    r[0]=lo[0]; r[1]=lo[1]; r[2]=lo[2]; r[3]=lo[3];
    r[4]=hi[0]; r[5]=hi[1]; r[6]=hi[2]; r[7]=hi[3];
    return r;
}

// ---------------- projection: one matrix, 4 rows per block. grid = 3*256 ----------------
__global__ __launch_bounds__(256) void proj_kernel(
    const float* __restrict__ query, const float* __restrict__ key_,
    const float* __restrict__ value,
    const float* __restrict__ Wq, const float* __restrict__ bq,
    const float* __restrict__ Wk, const float* __restrict__ bk,
    const float* __restrict__ Wv, const float* __restrict__ bv,
    float* __restrict__ Q, float* __restrict__ K, float* __restrict__ V,
    int grpPerMat)
{
    const int m  = blockIdx.x / grpPerMat;          // 0=q 1=k 2=v
    const int r0 = (blockIdx.x % grpPerMat) * 4;
    const float* x; const float* W; const float* bb; float* dst;
    if (m == 0)      { x = query; W = Wq; bb = bq; dst = Q; }
    else if (m == 1) { x = key_;  W = Wk; bb = bk; dst = K; }
    else             { x = value; W = Wv; bb = bv; dst = V; }
    const int c = threadIdx.x;
    const float b0 = bb[c];
    float a0 = b0, a1 = b0, a2 = b0, a3 = b0;
    for (int k = 0; k < DM; ++k) {
        const float w = W[k*DM + c];
        a0 = fmaf(x[(size_t)(r0+0)*DM + k], w, a0);   // uniform x -> scalar loads
        a1 = fmaf(x[(size_t)(r0+1)*DM + k], w, a1);
        a2 = fmaf(x[(size_t)(r0+2)*DM + k], w, a2);
        a3 = fmaf(x[(size_t)(r0+3)*DM + k], w, a3);
    }
    dst[(size_t)(r0+0)*DM + c] = a0;
    dst[(size_t)(r0+1)*DM + c] = a1;
    dst[(size_t)(r0+2)*DM + c] = a2;
    dst[(size_t)(r0+3)*DM + c] = a3;
}

// ---------------- s1[b,h,i,j] = inv * q_h(i).k_h(j), bf16 out ----------------
__global__ __launch_bounds__(256) void s1_kernel(
    const float* __restrict__ Q, const float* __restrict__ K,
    unsigned short* __restrict__ s1)
{
    const int tid = threadIdx.x;
    const int bh = blockIdx.y, b = bh >> 3, hh = bh & 7;
    const int ti = (blockIdx.x >> 3) * 64, tj = (blockIdx.x & 7) * 64;
    __shared__ float Qt[64][33];
    __shared__ float Kt[64][33];
    const int c = tid & 31, r0 = tid >> 5;
#pragma unroll
    for (int s = 0; s < 8; ++s) {
        Qt[r0 + 8*s][c] = Q[(size_t)(b*NN + ti + r0 + 8*s)*DM + hh*DKK + c];
        Kt[r0 + 8*s][c] = K[(size_t)(b*NN + tj + r0 + 8*s)*DM + hh*DKK + c];
    }
    __syncthreads();
    const int tx = tid & 15, ty = tid >> 4;
    float acc[4][4] = {};
#pragma unroll
    for (int k = 0; k < DKK; ++k) {
        float qv[4], kv[4];
#pragma unroll
        for (int u = 0; u < 4; ++u) { qv[u] = Qt[ty*4+u][k]; kv[u] = Kt[tx*4+u][k]; }
#pragma unroll
        for (int ri = 0; ri < 4; ++ri)
#pragma unroll
            for (int cj = 0; cj < 4; ++cj)
                acc[ri][cj] = fmaf(qv[ri], kv[cj], acc[ri][cj]);
    }
    const float inv = 0.17677669529663687f;
#pragma unroll
    for (int ri = 0; ri < 4; ++ri) {
        ushort4 o;
        o.x = f2bf(acc[ri][0]*inv); o.y = f2bf(acc[ri][1]*inv);
        o.z = f2bf(acc[ri][2]*inv); o.w = f2bf(acc[ri][3]*inv);
        *(ushort4*)(s1 + ((size_t)(b*HH + hh)*NN + ti + ty*4 + ri)*NN + tj + tx*4) = o;
    }
}

// ---------------- chunk kernel: ONE 128-j chunk per block. grid = rows*4 ----------------
// Plain local softmax (no online rescale); combine does the 4-way flash merge.
__global__ __launch_bounds__(256, 4) void chunk_kernel(
    const float* __restrict__ edges, const int* __restrict__ mask,
    const float* __restrict__ rkW1, const float* __restrict__ rkb1,
    const float* __restrict__ rkW2, const float* __restrict__ rkb2,
    const float* __restrict__ rvW1, const float* __restrict__ rvb1,
    const float* __restrict__ vvec,
    const float* __restrict__ Q, const float* __restrict__ K, const float* __restrict__ V,
    const unsigned short* __restrict__ s1u,
    float* __restrict__ ws_m, float* __restrict__ ws_z,
    float* __restrict__ ws_A, float* __restrict__ ws_O)
{
    const int bid = blockIdx.x;
    const int bi = bid >> 2, cq = bid & 3;   // row, j-quarter
    const int b  = bi >> 9;
    const int i  = bi & 511;
    const int j0 = cq*CH;
    const int tid = threadIdx.x;
    const int h = tid >> 5, l32 = tid & 31;          // softmax mapping
    const int wid = tid >> 6, lane = tid & 63;       // wave mapping (mfma)
    const int g = lane >> 4, q16 = lane & 15;
    const int team = tid >> 6, qq = tid & 63, hq = qq >> 3;  // accO mapping
    const int jj = tid & 127, half = tid >> 7;       // E-load / scores mapping
    const float inv = 0.17677669529663687f;

    // ---- LDS: unioned region + persistent buffers ----
    __shared__ __align__(16) unsigned char uni[17408];
    __shared__ __align__(16) unsigned short W1bf[64*68];     // [n=64][k=68], k 40..67 zero
    __shared__ __align__(16) float sc[HH*132];
    __shared__ __align__(16) float gKs[HH*DKK];
    __shared__ float c0Ks[HH];

    unsigned short* E   = (unsigned short*)uni;              // [128][68] bf16
    unsigned short* hvT = (unsigned short*)uni;              // [32][132] bf16 (overlays E)
    unsigned short* hk  = (unsigned short*)(uni + 8448);     // [128][34] bf16
    unsigned short* pb  = (unsigned short*)(uni + 8448);     // [16][132] bf16 (in hk space)
    float* wf    = (float*)uni;                              // prologue only
    float* paccA = (float*)uni;                              // [4][256] epilogue
    float* po    = (float*)(uni + 4096);                     // [4][256] epilogue

    const size_t ebase = (size_t)b*DE*NN*NN + (size_t)i*NN;
    const float* qrow = Q + (size_t)bi*DM;

    // ---- prefetch this chunk's edges into regs (lands under prologue) ----
    float ev[20];
    {
        const float* ep = edges + ebase + j0 + jj;
#pragma unroll
        for (int u = 0; u < 20; ++u) ev[u] = ep[(size_t)(half*20+u)*NN*NN];
    }

    // ---- prologue: wf, W1bf (combined W1k|W1v bf16, K-padded), bias regs ----
    wf[tid] = inv*(qrow[tid] + K[(size_t)bi*DM + tid]) + vvec[tid];
    {
        const int n = tid >> 2, qd = tid & 3;
#pragma unroll
        for (int kk = 0; kk < 17; ++kk) {
            const int k = qd*17 + kk;
            float v = 0.f;
            if (k < DE) v = (n < 32) ? rkW1[k*DHID + n] : rvW1[k*DHID + (n-32)];
            W1bf[n*68 + k] = f2bf(v);
        }
    }
    float biasv[4];
#pragma unroll
    for (int nt = 0; nt < 4; ++nt) {
        const int n = nt*16 + q16;
        biasv[nt] = (n < 32) ? rkb1[n] : rvb1[n-32];
    }
    __syncthreads();

    // ---- gK[h,t] = rkW2[t, h*32:].w[h,:]; c0K[h] = rkb2[h,:].w[h,:] ----
    {
        float acc = 0.f;
#pragma unroll
        for (int d4 = 0; d4 < DKK/4; ++d4) {
            const float4 w4 = *(const float4*)(rkW2 + (size_t)l32*DM + h*DKK + d4*4);
            const float4 f4 = *(const float4*)(&wf[h*DKK + d4*4]);
            acc = fmaf(w4.x, f4.x, acc); acc = fmaf(w4.y, f4.y, acc);
            acc = fmaf(w4.z, f4.z, acc); acc = fmaf(w4.w, f4.w, acc);
        }
        gKs[h*DKK + l32] = acc;
        if (tid < HH) {
            float a2 = 0.f;
#pragma unroll
            for (int d = 0; d < DKK; ++d)
                a2 = fmaf(rkb2[tid*DKK + d], wf[tid*DKK + d], a2);
            c0Ks[tid] = a2;
        }
    }
    __syncthreads();   // wf dead; E region free

    const float* vb = V + (size_t)b*NN*DM;
    const unsigned short* s1b = s1u + (size_t)b*HH*NN*NN + (size_t)i*NN;

    // ---- pack prefetched edges -> bf16 LDS [128][68] (cols 40..63 zero) ----
    {
        unsigned int* Ed = (unsigned int*)&E[jj*68 + half*20];
#pragma unroll
        for (int u = 0; u < 10; ++u) Ed[u] = pack2bf(ev[2*u], ev[2*u+1]);
        if (half) {
            unsigned int* Ez = (unsigned int*)&E[jj*68 + 40];
#pragma unroll
            for (int z = 0; z < 12; ++z) Ez[z] = 0u;
        }
    }
    __syncthreads();   // E ready

    // ---- h1 = E @ W1 (+bias) via MFMA: wave owns 32 j rows ----
    f32x4 acc[2][4];
#pragma unroll
    for (int jt = 0; jt < 2; ++jt) {
        const int jn = wid*32 + jt*16 + q16;
        short8v a0 = ld8(&E[jn*68 + g*8]);
        short8v a1 = ld8(&E[jn*68 + 32 + g*8]);
#pragma unroll
        for (int nt = 0; nt < 4; ++nt) {
            const unsigned short* wp = &W1bf[(q16 + nt*16)*68 + g*8];
            f32x4 c;
            c[0] = biasv[nt]; c[1] = biasv[nt]; c[2] = biasv[nt]; c[3] = biasv[nt];
            c = __builtin_amdgcn_mfma_f32_16x16x32_bf16(a0, ld8(wp), c, 0, 0, 0);
            c = __builtin_amdgcn_mfma_f32_16x16x32_bf16(a1, ld8(wp + 32), c, 0, 0, 0);
            acc[jt][nt] = c;
        }
    }
    __syncthreads();   // all E reads done before overwrite

    // ---- leaky + writeback: hk[j][t] and hvT[t][j] ----
#pragma unroll
    for (int jt = 0; jt < 2; ++jt) {
        const int jw = wid*32 + jt*16 + g*4;
#pragma unroll
        for (int nt = 0; nt < 4; ++nt) {
#pragma unroll
            for (int r = 0; r < 4; ++r) {
                float x = acc[jt][nt][r];
                x = x > 0.f ? x : 0.1f*x;
                const unsigned short us = f2bf(x);
                const int n = nt*16 + q16;
                if (n < 32) hk[(jw+r)*34 + n] = us;
                else        hvT[(n-32)*132 + (jw+r)] = us;
            }
        }
    }
    __syncthreads();   // hk/hvT ready

    // ---- scores: s2 (gK . h1k) + s1 + mask ----
    {
        unsigned int hku[16];
#pragma unroll
        for (int d = 0; d < 16; ++d) hku[d] = *(const unsigned int*)&hk[jj*34 + 2*d];
        const int mk = mask[b*NN + j0 + jj];
        float racc[4];
#pragma unroll
        for (int u = 0; u < 4; ++u) racc[u] = c0Ks[half*4 + u];
#pragma unroll
        for (int d = 0; d < 16; ++d) {
            const float lo = bf_lo(hku[d]), hi = bf_hi(hku[d]);
#pragma unroll
            for (int u = 0; u < 4; ++u) {
                const int hh = half*4 + u;
                racc[u] = fmaf(gKs[hh*DKK + 2*d],     lo, racc[u]);
                racc[u] = fmaf(gKs[hh*DKK + 2*d + 1], hi, racc[u]);
            }
        }
#pragma unroll
        for (int u = 0; u < 4; ++u) {
            const int hh = half*4 + u;
            float r = racc[u] + bf2f(s1b[(size_t)hh*NN*NN + j0 + jj]);
            if (mk == 0) r = -1e12f;
            sc[hh*132 + jj] = r;
        }
    }
    __syncthreads();

    // ---- local softmax (head h per 32-lane group), publish p bf16, emit m/Z ----
    {
        float sv[4];
        float mc = -3e38f;
#pragma unroll
        for (int k = 0; k < 4; ++k) { sv[k] = sc[h*132 + l32 + 32*k]; mc = fmaxf(mc, sv[k]); }
#pragma unroll
        for (int off = 16; off; off >>= 1) mc = fmaxf(mc, __shfl_xor(mc, off, 32));
        float zc = 0.f;
#pragma unroll
        for (int k = 0; k < 4; ++k) {
            const float e = __expf(sv[k] - mc);
            pb[h*132 + l32 + 32*k] = f2bf(e);
            zc += e;
        }
#pragma unroll
        for (int off = 16; off; off >>= 1) zc += __shfl_xor(zc, off, 32);
        if (l32 == 0) {
            ws_m[(size_t)bid*8 + h] = mc;
            ws_z[(size_t)bid*8 + h] = zc;
        }
    }
    __syncthreads();   // pb visible

    // ---- accA via MFMA (p[16x128] @ h1v[128x32], wave = K-quarter) + accO ----
    f32x4 accAf0 = {0.f,0.f,0.f,0.f}, accAf1 = {0.f,0.f,0.f,0.f};
    float aO0 = 0.f, aO1 = 0.f, aO2 = 0.f, aO3 = 0.f;
    {
        short8v pA = ld8(&pb[q16*132 + wid*32 + g*8]);
        short8v b0 = ld8(&hvT[q16*132 + wid*32 + g*8]);
        short8v b1 = ld8(&hvT[(16+q16)*132 + wid*32 + g*8]);
        accAf0 = __builtin_amdgcn_mfma_f32_16x16x32_bf16(pA, b0, accAf0, 0, 0, 0);
        accAf1 = __builtin_amdgcn_mfma_f32_16x16x32_bf16(pA, b1, accAf1, 0, 0, 0);

        // accO: channels qq*4..+3, j = j0 + team + 4*it
        const float* vrow = vb + (size_t)(j0 + team)*DM + qq*4;
        const unsigned short* ph = pb + hq*132 + team;
#pragma unroll 4
        for (int it = 0; it < 32; ++it) {
            const float p = bf2f(ph[4*it]);
            const float4 v4 = *(const float4*)(vrow + (size_t)it*4*DM);
            aO0 = fmaf(p, v4.x, aO0); aO1 = fmaf(p, v4.y, aO1);
            aO2 = fmaf(p, v4.z, aO2); aO3 = fmaf(p, v4.w, aO3);
        }
    }
    __syncthreads();   // pb/hvT consumed; epilogue overlays

    // ---- epilogue: reduce wave partials, emit raw (A, O) ----
    if (g < 2) {
#pragma unroll
        for (int r = 0; r < 4; ++r) {
            paccA[wid*256 + (4*g+r)*32 + q16]      = accAf0[r];
            paccA[wid*256 + (4*g+r)*32 + 16 + q16] = accAf1[r];
        }
    }
    *(float4*)(po + team*256 + qq*4) = make_float4(aO0, aO1, aO2, aO3);
    __syncthreads();

    ws_A[(size_t)bid*256 + tid] = paccA[tid] + paccA[256+tid] + paccA[512+tid] + paccA[768+tid];
    ws_O[(size_t)bid*256 + tid] = po[tid] + po[256+tid] + po[512+tid] + po[768+tid];
}

// ---------------- combine: 4-way flash merge, o2, Wo epilogue. 2 rows per block ----------------
__global__ __launch_bounds__(256) void combine_kernel(
    const float* __restrict__ rvW2, const float* __restrict__ rvb2,
    const float* __restrict__ Wo, const float* __restrict__ bo,
    const float* __restrict__ ws_m, const float* __restrict__ ws_z,
    const float* __restrict__ ws_A, const float* __restrict__ ws_O,
    float* __restrict__ out)
{
    const int bi0 = blockIdx.x * 2;
    const int tid = threadIdx.x;
    const int h = tid >> 5;
    __shared__ float A_l[2][DM], o_l[2][DM];
    __shared__ float wqs[2][4][HH], rzs[2][HH];

    if (tid < 16) {
        const int r = tid >> 3, hh = tid & 7;
        const int bi = bi0 + r;
        float mv[4], zv[4];
#pragma unroll
        for (int q = 0; q < 4; ++q) {
            mv[q] = ws_m[(size_t)(bi*4+q)*8 + hh];
            zv[q] = ws_z[(size_t)(bi*4+q)*8 + hh];
        }
        const float mm = fmaxf(fmaxf(mv[0], mv[1]), fmaxf(mv[2], mv[3]));
        float zt = 0.f;
#pragma unroll
        for (int q = 0; q < 4; ++q) {
            const float w = __expf(mv[q] - mm);
            wqs[r][q][hh] = w;
            zt = fmaf(zv[q], w, zt);
        }
        rzs[r][hh] = 1.f / zt;
    }
    __syncthreads();

    float o1v[2];
#pragma unroll
    for (int r = 0; r < 2; ++r) {
        const int bi = bi0 + r;
        const float rz = rzs[r][h];
        float A = 0.f, o1 = 0.f;
#pragma unroll
        for (int q = 0; q < 4; ++q) {
            const float w = wqs[r][q][h];
            A  = fmaf(w, ws_A[(size_t)(bi*4+q)*256 + tid], A);
            o1 = fmaf(w, ws_O[(size_t)(bi*4+q)*256 + tid], o1);
        }
        A_l[r][tid] = A * rz;
        o1v[r] = o1 * rz;
    }
    __syncthreads();

#pragma unroll
    for (int r = 0; r < 2; ++r) {
        float o2 = rvb2[tid];
#pragma unroll
        for (int t = 0; t < DHID; ++t)
            o2 = fmaf(A_l[r][h*DKK + t], rvW2[(size_t)t*DM + tid], o2);
        o_l[r][tid] = o1v[r] + o2;
    }
    __syncthreads();

    float acc0 = bo[tid], acc1 = acc0;
#pragma unroll 4
    for (int k = 0; k < DM; ++k) {
        const float w = Wo[(size_t)k*DM + tid];
        acc0 = fmaf(o_l[0][k], w, acc0);
        acc1 = fmaf(o_l[1][k], w, acc1);
    }
    out[(size_t)(bi0+0)*DM + tid] = acc0;
    out[(size_t)(bi0+1)*DM + tid] = acc1;
}

extern "C" void kernel_launch(void* const* d_in, const int* in_sizes, int n_in,
                              void* d_out, int out_size, void* d_ws, size_t ws_size,
                              hipStream_t stream) {
    const float* query = (const float*)d_in[0];
    const float* key_  = (const float*)d_in[1];
    const float* value = (const float*)d_in[2];
    const float* edges = (const float*)d_in[3];
    const int*   mask  = (const int*)d_in[4];
    const float* Wq = (const float*)d_in[5];
    const float* bq = (const float*)d_in[6];
    const float* Wk = (const float*)d_in[7];
    const float* bk = (const float*)d_in[8];
    const float* Wv = (const float*)d_in[9];
    const float* bv = (const float*)d_in[10];
    const float* Wo = (const float*)d_in[11];
    const float* bo = (const float*)d_in[12];
    const float* rkW1 = (const float*)d_in[13];
    const float* rkb1 = (const float*)d_in[14];
    const float* rkW2 = (const float*)d_in[15];
    const float* rkb2 = (const float*)d_in[16];
    const float* rvW1 = (const float*)d_in[17];
    const float* rvb1 = (const float*)d_in[18];
    const float* rvW2 = (const float*)d_in[19];
    const float* rvb2 = (const float*)d_in[20];
    // d_in[21] (u) is softmax-invariant -> unused
    const float* vvec = (const float*)d_in[22];

    const int rows = in_sizes[0] / DM;   // b*n = 1024
    const int nchunk = rows * 4;         // 4096

    float* Qw = (float*)d_ws;
    float* Kw = Qw + (size_t)rows*DM;
    float* Vw = Kw + (size_t)rows*DM;
    unsigned short* s1u = (unsigned short*)(Vw + (size_t)rows*DM);  // 8.4 MB bf16
    float* ws_m = (float*)(s1u + (size_t)2*HH*NN*NN);
    float* ws_z = ws_m + (size_t)nchunk*8;
    float* ws_A = ws_z + (size_t)nchunk*8;
    float* ws_O = ws_A + (size_t)nchunk*256;

    hipLaunchKernelGGL(proj_kernel, dim3(3*rows/4), dim3(256), 0, stream,
                       query, key_, value, Wq, bq, Wk, bk, Wv, bv, Qw, Kw, Vw, rows/4);
    hipLaunchKernelGGL(s1_kernel, dim3(64, 16), dim3(256), 0, stream,
                       Qw, Kw, s1u);
    hipLaunchKernelGGL(chunk_kernel, dim3(nchunk), dim3(256), 0, stream,
                       edges, mask, rkW1, rkb1, rkW2, rkb2, rvW1, rvb1,
                       vvec, Qw, Kw, Vw, s1u, ws_m, ws_z, ws_A, ws_O);
    hipLaunchKernelGGL(combine_kernel, dim3(rows/2), dim3(256), 0, stream,
                       rvW2, rvb2, Wo, bo, ws_m, ws_z, ws_A, ws_O, (float*)d_out);
}

// Round 11
// 107.603 us; speedup vs baseline: 1.9287x; 1.0747x over previous
//
#include <hip/hip_runtime.h>
#include <hip/hip_bf16.h>

#define HH 8
#define DKK 32
#define DM 256
#define NN 512
#define DE 40
#define DHID 32
#define CH 128

typedef __attribute__((ext_vector_type(4))) short short4v;
typedef __attribute__((ext_vector_type(8))) short short8v;
typedef __attribute__((ext_vector_type(4))) float f32x4;

__device__ __forceinline__ unsigned short f2bf(float x) {
    union { __hip_bfloat16 h; unsigned short u; } c;
    c.h = __float2bfloat16(x);
    return c.u;
}
__device__ __forceinline__ float bf2f(unsigned short u) {
    return __uint_as_float(((unsigned int)u) << 16);
}
__device__ __forceinline__ float bf_lo(unsigned int u){ return __uint_as_float(u << 16); }
__device__ __forceinline__ float bf_hi(unsigned int u){ return __uint_as_float(u & 0xffff0000u); }
__device__ __forceinline__ unsigned int pack2bf(float a, float b) {
    return (unsigned int)f2bf(a) | ((unsigned int)f2bf(b) << 16);
}
__device__ __forceinline__ short8v ld8(const unsigned short* p) {
    short4v lo = *(const short4v*)p;
    short4v hi = *(const short4v*)(p + 4);
    short8v r;
    r[0]=lo[0]; r[1]=lo[1]; r[2]=lo[2]; r[3]=lo[3];
    r[4]=hi[0]; r[5]=hi[1]; r[6]=hi[2]; r[7]=hi[3];
    return r;
}

// ---------------- w1: build combined W1k|W1v bf16 [64][68] + bias[64] once ----------------
__global__ __launch_bounds__(256) void w1_kernel(
    const float* __restrict__ rkW1, const float* __restrict__ rvW1,
    const float* __restrict__ rkb1, const float* __restrict__ rvb1,
    unsigned short* __restrict__ w1w, float* __restrict__ biasw)
{
    const int tid = threadIdx.x;
    const int n = tid >> 2, qd = tid & 3;
#pragma unroll
    for (int kk = 0; kk < 17; ++kk) {
        const int k = qd*17 + kk;
        float v = 0.f;
        if (k < DE) v = (n < 32) ? rkW1[k*DHID + n] : rvW1[k*DHID + (n-32)];
        w1w[n*68 + k] = f2bf(v);
    }
    if (tid < 64) biasw[tid] = (tid < 32) ? rkb1[tid] : rvb1[tid-32];
}

// ---------------- prep: per-row gK[h,t] and c0K[h] (once per row) ----------------
__global__ __launch_bounds__(256) void prep_kernel(
    const float* __restrict__ Q, const float* __restrict__ K,
    const float* __restrict__ vvec,
    const float* __restrict__ rkW2, const float* __restrict__ rkb2,
    float* __restrict__ gkw)
{
    const int bi = blockIdx.x;
    const int tid = threadIdx.x, h = tid >> 5, l32 = tid & 31;
    const float inv = 0.17677669529663687f;
    __shared__ __align__(16) float wf[DM];
    wf[tid] = inv*(Q[(size_t)bi*DM + tid] + K[(size_t)bi*DM + tid]) + vvec[tid];
    __syncthreads();
    float acc = 0.f;
#pragma unroll
    for (int d4 = 0; d4 < DKK/4; ++d4) {
        const float4 w4 = *(const float4*)(rkW2 + (size_t)l32*DM + h*DKK + d4*4);
        const float4 f4 = *(const float4*)(&wf[h*DKK + d4*4]);
        acc = fmaf(w4.x, f4.x, acc); acc = fmaf(w4.y, f4.y, acc);
        acc = fmaf(w4.z, f4.z, acc); acc = fmaf(w4.w, f4.w, acc);
    }
    gkw[(size_t)bi*264 + tid] = acc;          // gK flat [h*32+t]
    if (tid < HH) {
        float a2 = 0.f;
#pragma unroll
        for (int d = 0; d < DKK; ++d)
            a2 = fmaf(rkb2[tid*DKK + d], wf[tid*DKK + d], a2);
        gkw[(size_t)bi*264 + 256 + tid] = a2; // c0K
    }
}

// ---------------- projection: one matrix, 4 rows per block. grid = 3*256 ----------------
__global__ __launch_bounds__(256) void proj_kernel(
    const float* __restrict__ query, const float* __restrict__ key_,
    const float* __restrict__ value,
    const float* __restrict__ Wq, const float* __restrict__ bq,
    const float* __restrict__ Wk, const float* __restrict__ bk,
    const float* __restrict__ Wv, const float* __restrict__ bv,
    float* __restrict__ Q, float* __restrict__ K, float* __restrict__ V,
    int grpPerMat)
{
    const int m  = blockIdx.x / grpPerMat;          // 0=q 1=k 2=v
    const int r0 = (blockIdx.x % grpPerMat) * 4;
    const float* x; const float* W; const float* bb; float* dst;
    if (m == 0)      { x = query; W = Wq; bb = bq; dst = Q; }
    else if (m == 1) { x = key_;  W = Wk; bb = bk; dst = K; }
    else             { x = value; W = Wv; bb = bv; dst = V; }
    const int c = threadIdx.x;
    const float b0 = bb[c];
    float a0 = b0, a1 = b0, a2 = b0, a3 = b0;
    for (int k = 0; k < DM; ++k) {
        const float w = W[k*DM + c];
        a0 = fmaf(x[(size_t)(r0+0)*DM + k], w, a0);   // uniform x -> scalar loads
        a1 = fmaf(x[(size_t)(r0+1)*DM + k], w, a1);
        a2 = fmaf(x[(size_t)(r0+2)*DM + k], w, a2);
        a3 = fmaf(x[(size_t)(r0+3)*DM + k], w, a3);
    }
    dst[(size_t)(r0+0)*DM + c] = a0;
    dst[(size_t)(r0+1)*DM + c] = a1;
    dst[(size_t)(r0+2)*DM + c] = a2;
    dst[(size_t)(r0+3)*DM + c] = a3;
}

// ---------------- s1[b,h,i,j] = inv * q_h(i).k_h(j), bf16 out ----------------
__global__ __launch_bounds__(256) void s1_kernel(
    const float* __restrict__ Q, const float* __restrict__ K,
    unsigned short* __restrict__ s1)
{
    const int tid = threadIdx.x;
    const int bh = blockIdx.y, b = bh >> 3, hh = bh & 7;
    const int ti = (blockIdx.x >> 3) * 64, tj = (blockIdx.x & 7) * 64;
    __shared__ float Qt[64][33];
    __shared__ float Kt[64][33];
    const int c = tid & 31, r0 = tid >> 5;
#pragma unroll
    for (int s = 0; s < 8; ++s) {
        Qt[r0 + 8*s][c] = Q[(size_t)(b*NN + ti + r0 + 8*s)*DM + hh*DKK + c];
        Kt[r0 + 8*s][c] = K[(size_t)(b*NN + tj + r0 + 8*s)*DM + hh*DKK + c];
    }
    __syncthreads();
    const int tx = tid & 15, ty = tid >> 4;
    float acc[4][4] = {};
#pragma unroll
    for (int k = 0; k < DKK; ++k) {
        float qv[4], kv[4];
#pragma unroll
        for (int u = 0; u < 4; ++u) { qv[u] = Qt[ty*4+u][k]; kv[u] = Kt[tx*4+u][k]; }
#pragma unroll
        for (int ri = 0; ri < 4; ++ri)
#pragma unroll
            for (int cj = 0; cj < 4; ++cj)
                acc[ri][cj] = fmaf(qv[ri], kv[cj], acc[ri][cj]);
    }
    const float inv = 0.17677669529663687f;
#pragma unroll
    for (int ri = 0; ri < 4; ++ri) {
        ushort4 o;
        o.x = f2bf(acc[ri][0]*inv); o.y = f2bf(acc[ri][1]*inv);
        o.z = f2bf(acc[ri][2]*inv); o.w = f2bf(acc[ri][3]*inv);
        *(ushort4*)(s1 + ((size_t)(b*HH + hh)*NN + ti + ty*4 + ri)*NN + tj + tx*4) = o;
    }
}

// ---------------- chunk kernel: ONE 128-j chunk per block. grid = rows*4 ----------------
// Prologue is pure data copies (prep/w1 hoisted). 5 blocks/CU target.
__global__ __launch_bounds__(256, 5) void chunk_kernel(
    const float* __restrict__ edges, const int* __restrict__ mask,
    const float* __restrict__ vvec,
    const float* __restrict__ Q, const float* __restrict__ K, const float* __restrict__ V,
    const unsigned short* __restrict__ s1u,
    const unsigned short* __restrict__ w1w, const float* __restrict__ biasw,
    const float* __restrict__ gkw,
    float* __restrict__ ws_m, float* __restrict__ ws_z,
    float* __restrict__ ws_A, float* __restrict__ ws_O)
{
    const int bid = blockIdx.x;
    const int bi = bid >> 2, cq = bid & 3;   // row, j-quarter
    const int b  = bi >> 9;
    const int i  = bi & 511;
    const int j0 = cq*CH;
    const int tid = threadIdx.x;
    const int h = tid >> 5, l32 = tid & 31;          // softmax mapping
    const int wid = tid >> 6, lane = tid & 63;       // wave mapping (mfma)
    const int g = lane >> 4, q16 = lane & 15;
    const int team = tid >> 6, qq = tid & 63, hq = qq >> 3;  // accO mapping
    const int jj = tid & 127, half = tid >> 7;       // E-load / scores mapping

    // ---- LDS ----
    __shared__ __align__(16) unsigned char uni[17408];
    __shared__ __align__(16) unsigned short W1bf[64*68];
    __shared__ __align__(16) float sc[HH*132];
    __shared__ __align__(16) float gKs[HH*DKK];
    __shared__ float c0Ks[HH];
    __shared__ float bias_l[64];

    unsigned short* E   = (unsigned short*)uni;              // [128][68] bf16
    unsigned short* hvT = (unsigned short*)uni;              // [32][132] bf16 (overlays E)
    unsigned short* hk  = (unsigned short*)(uni + 8448);     // [128][34] bf16
    unsigned short* pb  = (unsigned short*)(uni + 8448);     // [16][132] bf16 (in hk space)
    float* paccA = (float*)uni;                              // [4][256] epilogue
    float* po    = (float*)(uni + 4096);                     // [4][256] epilogue

    const size_t ebase = (size_t)b*DE*NN*NN + (size_t)i*NN;

    // ---- prefetch this chunk's edges into regs (lands under the copies) ----
    float ev[20];
    {
        const float* ep = edges + ebase + j0 + jj;
#pragma unroll
        for (int u = 0; u < 20; ++u) ev[u] = ep[(size_t)(half*20+u)*NN*NN];
    }

    // ---- prologue: pure copies from ws ----
    {
        const unsigned int* src = (const unsigned int*)w1w;
        unsigned int* dst = (unsigned int*)W1bf;
#pragma unroll
        for (int u = tid; u < 2176; u += 256) dst[u] = src[u];
        const float* gsrc = gkw + (size_t)bi*264;
        gKs[tid] = gsrc[tid];
        if (tid < HH) c0Ks[tid] = gsrc[256 + tid];
        if (tid < 64) bias_l[tid] = biasw[tid];
    }
    __syncthreads();

    float biasv[4];
#pragma unroll
    for (int nt = 0; nt < 4; ++nt) biasv[nt] = bias_l[nt*16 + q16];

    const float* vb = V + (size_t)b*NN*DM;
    const unsigned short* s1b = s1u + (size_t)b*HH*NN*NN + (size_t)i*NN;

    // ---- pack prefetched edges -> bf16 LDS [128][68] (cols 40..63 zero) ----
    {
        unsigned int* Ed = (unsigned int*)&E[jj*68 + half*20];
#pragma unroll
        for (int u = 0; u < 10; ++u) Ed[u] = pack2bf(ev[2*u], ev[2*u+1]);
        if (half) {
            unsigned int* Ez = (unsigned int*)&E[jj*68 + 40];
#pragma unroll
            for (int z = 0; z < 12; ++z) Ez[z] = 0u;
        }
    }
    __syncthreads();   // E ready

    // ---- h1 = E @ W1 (+bias) via MFMA: wave owns 32 j rows ----
    f32x4 acc[2][4];
#pragma unroll
    for (int jt = 0; jt < 2; ++jt) {
        const int jn = wid*32 + jt*16 + q16;
        short8v a0 = ld8(&E[jn*68 + g*8]);
        short8v a1 = ld8(&E[jn*68 + 32 + g*8]);
#pragma unroll
        for (int nt = 0; nt < 4; ++nt) {
            const unsigned short* wp = &W1bf[(q16 + nt*16)*68 + g*8];
            f32x4 c;
            c[0] = biasv[nt]; c[1] = biasv[nt]; c[2] = biasv[nt]; c[3] = biasv[nt];
            c = __builtin_amdgcn_mfma_f32_16x16x32_bf16(a0, ld8(wp), c, 0, 0, 0);
            c = __builtin_amdgcn_mfma_f32_16x16x32_bf16(a1, ld8(wp + 32), c, 0, 0, 0);
            acc[jt][nt] = c;
        }
    }
    __syncthreads();   // all E reads done before overwrite

    // ---- leaky + writeback: hk[j][t] and hvT[t][j] ----
#pragma unroll
    for (int jt = 0; jt < 2; ++jt) {
        const int jw = wid*32 + jt*16 + g*4;
#pragma unroll
        for (int nt = 0; nt < 4; ++nt) {
#pragma unroll
            for (int r = 0; r < 4; ++r) {
                float x = acc[jt][nt][r];
                x = x > 0.f ? x : 0.1f*x;
                const unsigned short us = f2bf(x);
                const int n = nt*16 + q16;
                if (n < 32) hk[(jw+r)*34 + n] = us;
                else        hvT[(n-32)*132 + (jw+r)] = us;
            }
        }
    }
    __syncthreads();   // hk/hvT ready

    // ---- scores: s2 (gK . h1k) + s1 + mask ----
    {
        unsigned int hku[16];
#pragma unroll
        for (int d = 0; d < 16; ++d) hku[d] = *(const unsigned int*)&hk[jj*34 + 2*d];
        const int mk = mask[b*NN + j0 + jj];
        float racc[4];
#pragma unroll
        for (int u = 0; u < 4; ++u) racc[u] = c0Ks[half*4 + u];
#pragma unroll
        for (int d = 0; d < 16; ++d) {
            const float lo = bf_lo(hku[d]), hi = bf_hi(hku[d]);
#pragma unroll
            for (int u = 0; u < 4; ++u) {
                const int hh = half*4 + u;
                racc[u] = fmaf(gKs[hh*DKK + 2*d],     lo, racc[u]);
                racc[u] = fmaf(gKs[hh*DKK + 2*d + 1], hi, racc[u]);
            }
        }
#pragma unroll
        for (int u = 0; u < 4; ++u) {
            const int hh = half*4 + u;
            float r = racc[u] + bf2f(s1b[(size_t)hh*NN*NN + j0 + jj]);
            if (mk == 0) r = -1e12f;
            sc[hh*132 + jj] = r;
        }
    }
    __syncthreads();

    // ---- local softmax (head h per 32-lane group), publish p bf16, emit m/Z ----
    {
        float sv[4];
        float mc = -3e38f;
#pragma unroll
        for (int k = 0; k < 4; ++k) { sv[k] = sc[h*132 + l32 + 32*k]; mc = fmaxf(mc, sv[k]); }
#pragma unroll
        for (int off = 16; off; off >>= 1) mc = fmaxf(mc, __shfl_xor(mc, off, 32));
        float zc = 0.f;
#pragma unroll
        for (int k = 0; k < 4; ++k) {
            const float e = __expf(sv[k] - mc);
            pb[h*132 + l32 + 32*k] = f2bf(e);
            zc += e;
        }
#pragma unroll
        for (int off = 16; off; off >>= 1) zc += __shfl_xor(zc, off, 32);
        if (l32 == 0) {
            ws_m[(size_t)bid*8 + h] = mc;
            ws_z[(size_t)bid*8 + h] = zc;
        }
    }
    __syncthreads();   // pb visible

    // ---- accA via MFMA (p[16x128] @ h1v[128x32], wave = K-quarter) + accO ----
    f32x4 accAf0 = {0.f,0.f,0.f,0.f}, accAf1 = {0.f,0.f,0.f,0.f};
    float aO0 = 0.f, aO1 = 0.f, aO2 = 0.f, aO3 = 0.f;
    {
        short8v pA = ld8(&pb[q16*132 + wid*32 + g*8]);
        short8v b0 = ld8(&hvT[q16*132 + wid*32 + g*8]);
        short8v b1 = ld8(&hvT[(16+q16)*132 + wid*32 + g*8]);
        accAf0 = __builtin_amdgcn_mfma_f32_16x16x32_bf16(pA, b0, accAf0, 0, 0, 0);
        accAf1 = __builtin_amdgcn_mfma_f32_16x16x32_bf16(pA, b1, accAf1, 0, 0, 0);

        // accO: channels qq*4..+3, j = j0 + team + 4*it
        const float* vrow = vb + (size_t)(j0 + team)*DM + qq*4;
        const unsigned short* ph = pb + hq*132 + team;
#pragma unroll 4
        for (int it = 0; it < 32; ++it) {
            const float p = bf2f(ph[4*it]);
            const float4 v4 = *(const float4*)(vrow + (size_t)it*4*DM);
            aO0 = fmaf(p, v4.x, aO0); aO1 = fmaf(p, v4.y, aO1);
            aO2 = fmaf(p, v4.z, aO2); aO3 = fmaf(p, v4.w, aO3);
        }
    }
    __syncthreads();   // pb/hvT consumed; epilogue overlays

    // ---- epilogue: reduce wave partials, emit raw (A, O) ----
    if (g < 2) {
#pragma unroll
        for (int r = 0; r < 4; ++r) {
            paccA[wid*256 + (4*g+r)*32 + q16]      = accAf0[r];
            paccA[wid*256 + (4*g+r)*32 + 16 + q16] = accAf1[r];
        }
    }
    *(float4*)(po + team*256 + qq*4) = make_float4(aO0, aO1, aO2, aO3);
    __syncthreads();

    ws_A[(size_t)bid*256 + tid] = paccA[tid] + paccA[256+tid] + paccA[512+tid] + paccA[768+tid];
    ws_O[(size_t)bid*256 + tid] = po[tid] + po[256+tid] + po[512+tid] + po[768+tid];
}

// ---------------- combine: 4-way flash merge, o2, Wo epilogue. 2 rows per block ----------------
__global__ __launch_bounds__(256) void combine_kernel(
    const float* __restrict__ rvW2, const float* __restrict__ rvb2,
    const float* __restrict__ Wo, const float* __restrict__ bo,
    const float* __restrict__ ws_m, const float* __restrict__ ws_z,
    const float* __restrict__ ws_A, const float* __restrict__ ws_O,
    float* __restrict__ out)
{
    const int bi0 = blockIdx.x * 2;
    const int tid = threadIdx.x;
    const int h = tid >> 5;
    __shared__ float A_l[2][DM], o_l[2][DM];
    __shared__ float wqs[2][4][HH], rzs[2][HH];

    if (tid < 16) {
        const int r = tid >> 3, hh = tid & 7;
        const int bi = bi0 + r;
        float mv[4], zv[4];
#pragma unroll
        for (int q = 0; q < 4; ++q) {
            mv[q] = ws_m[(size_t)(bi*4+q)*8 + hh];
            zv[q] = ws_z[(size_t)(bi*4+q)*8 + hh];
        }
        const float mm = fmaxf(fmaxf(mv[0], mv[1]), fmaxf(mv[2], mv[3]));
        float zt = 0.f;
#pragma unroll
        for (int q = 0; q < 4; ++q) {
            const float w = __expf(mv[q] - mm);
            wqs[r][q][hh] = w;
            zt = fmaf(zv[q], w, zt);
        }
        rzs[r][hh] = 1.f / zt;
    }
    __syncthreads();

    float o1v[2];
#pragma unroll
    for (int r = 0; r < 2; ++r) {
        const int bi = bi0 + r;
        const float rz = rzs[r][h];
        float A = 0.f, o1 = 0.f;
#pragma unroll
        for (int q = 0; q < 4; ++q) {
            const float w = wqs[r][q][h];
            A  = fmaf(w, ws_A[(size_t)(bi*4+q)*256 + tid], A);
            o1 = fmaf(w, ws_O[(size_t)(bi*4+q)*256 + tid], o1);
        }
        A_l[r][tid] = A * rz;
        o1v[r] = o1 * rz;
    }
    __syncthreads();

#pragma unroll
    for (int r = 0; r < 2; ++r) {
        float o2 = rvb2[tid];
#pragma unroll
        for (int t = 0; t < DHID; ++t)
            o2 = fmaf(A_l[r][h*DKK + t], rvW2[(size_t)t*DM + tid], o2);
        o_l[r][tid] = o1v[r] + o2;
    }
    __syncthreads();

    float acc0 = bo[tid], acc1 = acc0;
#pragma unroll 4
    for (int k = 0; k < DM; ++k) {
        const float w = Wo[(size_t)k*DM + tid];
        acc0 = fmaf(o_l[0][k], w, acc0);
        acc1 = fmaf(o_l[1][k], w, acc1);
    }
    out[(size_t)(bi0+0)*DM + tid] = acc0;
    out[(size_t)(bi0+1)*DM + tid] = acc1;
}

extern "C" void kernel_launch(void* const* d_in, const int* in_sizes, int n_in,
                              void* d_out, int out_size, void* d_ws, size_t ws_size,
                              hipStream_t stream) {
    const float* query = (const float*)d_in[0];
    const float* key_  = (const float*)d_in[1];
    const float* value = (const float*)d_in[2];
    const float* edges = (const float*)d_in[3];
    const int*   mask  = (const int*)d_in[4];
    const float* Wq = (const float*)d_in[5];
    const float* bq = (const float*)d_in[6];
    const float* Wk = (const float*)d_in[7];
    const float* bk = (const float*)d_in[8];
    const float* Wv = (const float*)d_in[9];
    const float* bv = (const float*)d_in[10];
    const float* Wo = (const float*)d_in[11];
    const float* bo = (const float*)d_in[12];
    const float* rkW1 = (const float*)d_in[13];
    const float* rkb1 = (const float*)d_in[14];
    const float* rkW2 = (const float*)d_in[15];
    const float* rkb2 = (const float*)d_in[16];
    const float* rvW1 = (const float*)d_in[17];
    const float* rvb1 = (const float*)d_in[18];
    const float* rvW2 = (const float*)d_in[19];
    const float* rvb2 = (const float*)d_in[20];
    // d_in[21] (u) is softmax-invariant -> unused
    const float* vvec = (const float*)d_in[22];

    const int rows = in_sizes[0] / DM;   // b*n = 1024
    const int nchunk = rows * 4;         // 4096

    float* Qw = (float*)d_ws;
    float* Kw = Qw + (size_t)rows*DM;
    float* Vw = Kw + (size_t)rows*DM;
    unsigned short* s1u = (unsigned short*)(Vw + (size_t)rows*DM);  // 8.4 MB bf16
    float* ws_m = (float*)(s1u + (size_t)2*HH*NN*NN);
    float* ws_z = ws_m + (size_t)nchunk*8;
    float* ws_A = ws_z + (size_t)nchunk*8;
    float* ws_O = ws_A + (size_t)nchunk*256;
    unsigned short* w1w = (unsigned short*)(ws_O + (size_t)nchunk*256);  // 64*68 bf16
    float* biasw = (float*)(w1w + 64*68 + 32);
    float* gkw   = biasw + 64;                                      // rows*264 f32

    hipLaunchKernelGGL(w1_kernel, dim3(1), dim3(256), 0, stream,
                       rkW1, rvW1, rkb1, rvb1, w1w, biasw);
    hipLaunchKernelGGL(proj_kernel, dim3(3*rows/4), dim3(256), 0, stream,
                       query, key_, value, Wq, bq, Wk, bk, Wv, bv, Qw, Kw, Vw, rows/4);
    hipLaunchKernelGGL(s1_kernel, dim3(64, 16), dim3(256), 0, stream,
                       Qw, Kw, s1u);
    hipLaunchKernelGGL(prep_kernel, dim3(rows), dim3(256), 0, stream,
                       Qw, Kw, vvec, rkW2, rkb2, gkw);
    hipLaunchKernelGGL(chunk_kernel, dim3(nchunk), dim3(256), 0, stream,
                       edges, mask, vvec, Qw, Kw, Vw, s1u, w1w, biasw, gkw,
                       ws_m, ws_z, ws_A, ws_O);
    hipLaunchKernelGGL(combine_kernel, dim3(rows/2), dim3(256), 0, stream,
                       rvW2, rvb2, Wo, bo, ws_m, ws_z, ws_A, ws_O, (float*)d_out);
}